// Round 1
// baseline (15514.874 us; speedup 1.0000x reference)
//
#include <hip/hip_runtime.h>
#include <math.h>

#define NB 8
#define NP 4096
#define NCIN 64
#define NS 1024
#define NK 32
#define NC 128
#define NJ 5
#define NDEPTH 2
#define NH 4
#define NPTS (NB*NS)       /* 8192 groups */
#define NM (NPTS*NK)       /* 262144 rows */
#define EPSF 1e-5f

// ---------------------------------------------------------------- FPS
__global__ __launch_bounds__(1024) void k_fps(const float* __restrict__ xyz,
                                              float* __restrict__ newxyz) {
  const int b = blockIdx.x;
  const int t = threadIdx.x;
  const float* X = xyz + (size_t)b * NP * 3;
  float px[4], py[4], pz[4], dist[4];
#pragma unroll
  for (int i = 0; i < 4; ++i) {
    int n = t + 1024 * i;
    px[i] = X[3*n+0]; py[i] = X[3*n+1]; pz[i] = X[3*n+2];
    dist[i] = 1e10f;
  }
  __shared__ float cen[4];
  __shared__ float wv[16];
  __shared__ int   wi[16];
  __shared__ int   sfar;
  int far = 0;
  for (int s = 0; s < NS; ++s) {
    if (t == 0) {
      float cx = X[3*far+0], cy = X[3*far+1], cz = X[3*far+2];
      cen[0]=cx; cen[1]=cy; cen[2]=cz;
      float* o = newxyz + ((size_t)b*NS + s)*3;
      o[0]=cx; o[1]=cy; o[2]=cz;
    }
    __syncthreads();
    float cx=cen[0], cy=cen[1], cz=cen[2];
    float bv = -1.0f; int bi = 0x7fffffff;
#pragma unroll
    for (int i = 0; i < 4; ++i) {
      float dx=px[i]-cx, dy=py[i]-cy, dz=pz[i]-cz;
      float d = dx*dx + dy*dy + dz*dz;
      float nd = fminf(dist[i], d);
      dist[i] = nd;
      if (nd > bv) { bv = nd; bi = t + 1024*i; }   // ascending n: strict > keeps lowest idx
    }
#pragma unroll
    for (int off = 32; off; off >>= 1) {
      float ov = __shfl_xor(bv, off);
      int   oi = __shfl_xor(bi, off);
      if (ov > bv || (ov == bv && oi < bi)) { bv = ov; bi = oi; }
    }
    if ((t & 63) == 0) { wv[t>>6] = bv; wi[t>>6] = bi; }
    __syncthreads();
    if (t == 0) {
      for (int w = 1; w < 16; ++w)
        if (wv[w] > bv || (wv[w] == bv && wi[w] < bi)) { bv = wv[w]; bi = wi[w]; }
      sfar = bi;
    }
    __syncthreads();
    far = sfar;
  }
}

// ---------------------------------------------------------------- KNN (top-32 smallest d2, stable)
__global__ __launch_bounds__(256) void k_knn(const float* __restrict__ xyz,
                                             const float* __restrict__ newxyz,
                                             int* __restrict__ knn_idx,
                                             float* __restrict__ gnorm) {
  const int p = blockIdx.x;
  const int b = p >> 10;
  const int t = threadIdx.x;
  const float* X = xyz + (size_t)b * NP * 3;
  __shared__ float d2[NP];
  __shared__ float rwv[4];
  __shared__ int   rwi[4];
  float cx = newxyz[3*p+0], cy = newxyz[3*p+1], cz = newxyz[3*p+2];
  float sc = cx*cx + cy*cy + cz*cz;
  for (int n = t; n < NP; n += 256) {
    float x = X[3*n+0], y = X[3*n+1], z = X[3*n+2];
    float sx = x*x + y*y + z*z;
    float dot = cx*x + cy*y + cz*z;
    d2[n] = sc + sx - 2.0f*dot;
  }
  __syncthreads();
  for (int it = 0; it < NK; ++it) {
    float bv = 3.0e38f; int bi = 0x7fffffff;
    for (int n = t; n < NP; n += 256) {
      float v = d2[n];
      if (v < bv) { bv = v; bi = n; }   // ascending n per thread
    }
#pragma unroll
    for (int off = 32; off; off >>= 1) {
      float ov = __shfl_xor(bv, off);
      int   oi = __shfl_xor(bi, off);
      if (ov < bv || (ov == bv && oi < bi)) { bv = ov; bi = oi; }
    }
    if ((t & 63) == 0) { rwv[t>>6] = bv; rwi[t>>6] = bi; }
    __syncthreads();
    if (t == 0) {
      for (int w = 1; w < 4; ++w)
        if (rwv[w] < bv || (rwv[w] == bv && rwi[w] < bi)) { bv = rwv[w]; bi = rwi[w]; }
      d2[bi] = 3.3e38f;
      knn_idx[p*NK + it] = bi;
      float* g = gnorm + ((size_t)p*NK + it)*3;
      g[0] = X[3*bi+0] - cx;
      g[1] = X[3*bi+1] - cy;
      g[2] = X[3*bi+2] - cz;
    }
    __syncthreads();
  }
}

// ---------------------------------------------------------------- MLP layer 1 (gather 67-ch input)
__global__ __launch_bounds__(256) void k_layer1(const float* __restrict__ points,
                                                const int* __restrict__ knn_idx,
                                                const float* __restrict__ gnorm,
                                                const float* __restrict__ w1,
                                                float* __restrict__ y,
                                                float* __restrict__ stats) {
  const int r0 = blockIdx.x * 64;
  const int t = threadIdx.x;
  __shared__ float Xs[64][69];
  __shared__ float Ws[64][69];
  __shared__ int nid[64];
  __shared__ float ps[4][64], pss[4][64];
  if (t < 64) nid[t] = knn_idx[r0 + t];
  __syncthreads();
  for (int idx = t; idx < 64*67; idx += 256) {
    int r = idx / 67, c = idx % 67;
    int row = r0 + r;
    float v;
    if (c < 3) v = gnorm[(size_t)row*3 + c];
    else {
      int bb = row >> 15;            // row/(S*K)
      int n = nid[r];
      v = points[((size_t)bb*NP + n)*NCIN + (c-3)];
    }
    Xs[r][c] = v;
  }
  for (int idx = t; idx < 64*67; idx += 256) {
    int o = idx / 67, c = idx % 67;
    Ws[o][c] = w1[idx];
  }
  __syncthreads();
  const int col = t & 63;
  const int rb  = t >> 6;
  float s1 = 0.f, s2 = 0.f;
  for (int i = 0; i < 16; ++i) {
    int r = rb + 4*i;
    float acc = 0.f;
#pragma unroll
    for (int c = 0; c < 67; ++c) acc += Xs[r][c] * Ws[col][c];
    y[(size_t)(r0 + r)*64 + col] = acc;
    s1 += acc; s2 += acc*acc;
  }
  ps[rb][col] = s1; pss[rb][col] = s2;
  __syncthreads();
  if (t < 64) {
    float a = ps[0][t]+ps[1][t]+ps[2][t]+ps[3][t];
    float q = pss[0][t]+pss[1][t]+pss[2][t]+pss[3][t];
    atomicAdd(&stats[t], a);
    atomicAdd(&stats[64 + t], q);
  }
}

// ---------------------------------------------------------------- MLP layers 2/3 (affine+relu folded on load)
template <int COUT>
__global__ __launch_bounds__(256) void k_layer(const float* __restrict__ xin,
                                               const float* __restrict__ aff,
                                               const float* __restrict__ w,
                                               float* __restrict__ y,
                                               float* __restrict__ stats) {
  const int r0 = blockIdx.x * 64;
  const int t = threadIdx.x;
  __shared__ float Xs[64][65];
  __shared__ float Ws[COUT][65];
  __shared__ float sa[64], sb[64];
  constexpr int NTR = 256 / COUT;
  __shared__ float ps[NTR][COUT], pss[NTR][COUT];
  if (t < 64) { sa[t] = aff[t]; sb[t] = aff[64 + t]; }
  __syncthreads();
  for (int idx = t; idx < 64*64; idx += 256) {
    int r = idx >> 6, c = idx & 63;
    float v = xin[(size_t)r0*64 + idx];
    Xs[r][c] = fmaxf(sa[c]*v + sb[c], 0.0f);
  }
  for (int idx = t; idx < COUT*64; idx += 256) {
    int o = idx >> 6, c = idx & 63;
    Ws[o][c] = w[idx];
  }
  __syncthreads();
  const int col = t & (COUT-1);
  const int rb  = t / COUT;
  float s1 = 0.f, s2 = 0.f;
  for (int i = 0; i < 64/NTR; ++i) {
    int r = rb + NTR*i;
    float acc = 0.f;
#pragma unroll
    for (int c = 0; c < 64; ++c) acc += Xs[r][c] * Ws[col][c];
    y[(size_t)(r0 + r)*COUT + col] = acc;
    s1 += acc; s2 += acc*acc;
  }
  ps[rb][col] = s1; pss[rb][col] = s2;
  __syncthreads();
  if (t < COUT) {
    float a = 0.f, q = 0.f;
    for (int n = 0; n < NTR; ++n) { a += ps[n][t]; q += pss[n][t]; }
    atomicAdd(&stats[t], a);
    atomicAdd(&stats[COUT + t], q);
  }
}

// ---------------------------------------------------------------- BN stats -> affine
__global__ void k_finalize(const float* __restrict__ stats, const float* __restrict__ g,
                           const float* __restrict__ b, float* __restrict__ aff, int cout) {
  int t = threadIdx.x;
  if (t < cout) {
    const float inv = 1.0f / (float)NM;
    float m = stats[t] * inv;
    float var = stats[cout + t] * inv - m*m;
    float a = g[t] * rsqrtf(var + EPSF);
    aff[t] = a;
    aff[cout + t] = b[t] - m * a;
  }
}

// ---------------------------------------------------------------- fused per-group: Laplacian + wavelet mix + 2x (LN,MHA,LN) + maxpool
__global__ __launch_bounds__(256) void k_group(
    const float* __restrict__ h3, const float* __restrict__ aff3,
    const float* __restrict__ gnorm,
    const float* __restrict__ wsW, const float* __restrict__ wb,
    const float* __restrict__ alpha, const float* __restrict__ wqkv,
    const float* __restrict__ wo,
    const float* __restrict__ ln1g, const float* __restrict__ ln1b,
    const float* __restrict__ ln2g, const float* __restrict__ ln2b,
    float* __restrict__ out) {
  const int p = blockIdx.x;
  const int t = threadIdx.x;
  __shared__ float hcur[NK*NC];
  __shared__ float bufA[NK*NC];
  __shared__ float bufB[NK*NC];
  __shared__ float mats[4][NK*NK];   // total exactly 64 KiB

  if (t < NK*3) mats[0][t] = gnorm[(size_t)p*NK*3 + t];   // px
  const float* h3p = h3 + (size_t)p * (NK*NC);
  for (int i = t; i < NK*NC; i += 256) {
    int c = i & (NC-1);
    hcur[i] = fmaxf(aff3[c]*h3p[i] + aff3[NC + c], 0.0f);  // pf
  }
  __syncthreads();
  // dd -> mats[2]
  for (int i = t; i < NK*NK; i += 256) {
    int k = i >> 5, l = i & 31;
    float dx = mats[0][k*3+0] - mats[0][l*3+0];
    float dy = mats[0][k*3+1] - mats[0][l*3+1];
    float dz = mats[0][k*3+2] - mats[0][l*3+2];
    mats[2][i] = dx*dx + dy*dy + dz*dz;
  }
  __syncthreads();
  // sigma = mean sqrt(dd+1e-12)
  float part = 0.0f;
  for (int i = t; i < NK*NK; i += 256) part += sqrtf(mats[2][i] + 1e-12f);
#pragma unroll
  for (int off = 32; off; off >>= 1) part += __shfl_xor(part, off);
  if ((t & 63) == 0) bufA[t >> 6] = part;
  __syncthreads();
  if (t == 0) {
    float sg = (bufA[0]+bufA[1]+bufA[2]+bufA[3]) * (1.0f/1024.0f);
    bufA[8] = 2.0f*sg*sg + 1e-12f;
  }
  __syncthreads();
  const float denom = bufA[8];
  for (int i = t; i < NK*NK; i += 256) mats[2][i] = expf(-mats[2][i] / denom);  // A
  __syncthreads();
  if (t < NK) {
    float s = 0.f;
    for (int l = 0; l < NK; ++l) s += mats[2][t*NK + l];
    mats[0][t] = rsqrtf(s + 1e-12f);   // dinv
  }
  __syncthreads();
  for (int i = t; i < NK*NK; i += 256) {          // L -> mats[1] (persistent)
    int k = i >> 5, l = i & 31;
    float v = -(mats[0][k] * mats[2][i] * mats[0][l]);
    if (k == l) v += 1.0f;
    mats[1][i] = v;
  }
  __syncthreads();

  for (int d = 0; d < NDEPTH; ++d) {
    for (int i = t; i < NK*NC; i += 256) bufB[i] = 0.0f;   // mix
    __syncthreads();
    for (int j = 0; j < NJ; ++j) {
      const float sj = -0.05f * (float)(1 << j);
      for (int i = t; i < NK*NK; i += 256) {       // T = I + M ; acc = M
        float m = sj * mats[1][i];
        mats[2][i] = (((i >> 5) == (i & 31)) ? 1.0f : 0.0f) + m;
        mats[0][i] = m;
      }
      __syncthreads();
      float* acc = mats[0];
      float* accN = mats[3];
      for (int m = 2; m <= 4; ++m) {
        const float fm = (float)m;
        for (int i = t; i < NK*NK; i += 256) {
          int k = i >> 5, l = i & 31;
          float a = 0.f;
#pragma unroll
          for (int q = 0; q < NK; ++q) a += acc[k*NK + q] * (sj * mats[1][q*NK + l]);
          float v = a / fm;
          accN[i] = v;
          mats[2][i] += v;
        }
        { float* tp = acc; acc = accN; accN = tp; }
        __syncthreads();
      }
      // tmp = T @ hcur
      for (int i = t; i < NK*NC; i += 256) {
        int k = i >> 7, c = i & (NC-1);
        float a = 0.f;
#pragma unroll
        for (int l = 0; l < NK; ++l) a += mats[2][k*NK + l] * hcur[l*NC + c];
        bufA[i] = a;
      }
      __syncthreads();
      const float alj = alpha[d*NJ + j];
      const float* Wj = wsW + (((size_t)(d*NJ + j)) << 14);
      for (int i = t; i < NK*NC; i += 256) {
        int k = i >> 7, o = i & (NC-1);
        float a = 0.f;
        for (int c = 0; c < NC; ++c) a += bufA[k*NC + c] * Wj[c*NC + o];
        bufB[i] += alj * a;
      }
      __syncthreads();
    }
    // u = hcur + relu(mix + wb)
    for (int i = t; i < NK*NC; i += 256) {
      int o = i & (NC-1);
      bufB[i] = hcur[i] + fmaxf(bufB[i] + wb[d*NC + o], 0.0f);
    }
    __syncthreads();
    { // LN1 -> hcur
      const int k = t >> 3, e = t & 7;
      float s = 0.f;
#pragma unroll
      for (int ii = 0; ii < 16; ++ii) s += bufB[k*NC + e + 8*ii];
      s += __shfl_xor(s, 1); s += __shfl_xor(s, 2); s += __shfl_xor(s, 4);
      float mu = s * (1.0f/128.0f);
      float vs = 0.f;
#pragma unroll
      for (int ii = 0; ii < 16; ++ii) { float dx = bufB[k*NC + e + 8*ii] - mu; vs += dx*dx; }
      vs += __shfl_xor(vs, 1); vs += __shfl_xor(vs, 2); vs += __shfl_xor(vs, 4);
      float rs = rsqrtf(vs*(1.0f/128.0f) + EPSF);
#pragma unroll
      for (int ii = 0; ii < 16; ++ii) {
        int o = e + 8*ii;
        hcur[k*NC + o] = (bufB[k*NC + o] - mu)*rs*ln1g[d*NC + o] + ln1b[d*NC + o];
      }
    }
    __syncthreads();
    // attention (per head); o accumulates into bufB
    const float* Wq = wqkv + (size_t)d*NC*384;
    for (int h = 0; h < NH; ++h) {
      for (int i = t; i < 3*NK*32; i += 256) {
        int comp = i >> 10;
        int r = i & 1023;
        int k = r >> 5, dd = r & 31;
        int colq = comp*NC + h*32 + dd;
        float a = 0.f;
        for (int c = 0; c < NC; ++c) a += hcur[k*NC + c] * Wq[c*384 + colq];
        bufA[i] = a;
      }
      __syncthreads();
      for (int i = t; i < NK*NK; i += 256) {
        int k = i >> 5, l = i & 31;
        float a = 0.f;
#pragma unroll
        for (int dd = 0; dd < 32; ++dd) a += bufA[k*32 + dd] * bufA[1024 + l*32 + dd];
        bufA[3072 + i] = a / 5.656854249492381f;
      }
      __syncthreads();
      if (t < NK) {
        float mx = -3.4e38f;
        for (int l = 0; l < NK; ++l) mx = fmaxf(mx, bufA[3072 + t*NK + l]);
        float s = 0.f;
        for (int l = 0; l < NK; ++l) { float e = expf(bufA[3072 + t*NK + l] - mx); bufA[3072 + t*NK + l] = e; s += e; }
        for (int l = 0; l < NK; ++l) bufA[3072 + t*NK + l] /= s;
      }
      __syncthreads();
      for (int i = t; i < NK*32; i += 256) {
        int k = i >> 5, dd = i & 31;
        float a = 0.f;
#pragma unroll
        for (int l = 0; l < NK; ++l) a += bufA[3072 + k*NK + l] * bufA[2048 + l*32 + dd];
        bufB[k*NC + h*32 + dd] = a;
      }
      __syncthreads();
    }
    // proj + residual + LN2
    for (int i = t; i < NK*NC; i += 256) {
      int k = i >> 7, o2 = i & (NC-1);
      float a = 0.f;
      for (int c = 0; c < NC; ++c) a += bufB[k*NC + c] * wo[(size_t)d*NC*NC + c*NC + o2];
      bufA[i] = a;
    }
    __syncthreads();
    for (int i = t; i < NK*NC; i += 256) bufB[i] = hcur[i] + bufA[i];
    __syncthreads();
    {
      const int k = t >> 3, e = t & 7;
      float s = 0.f;
#pragma unroll
      for (int ii = 0; ii < 16; ++ii) s += bufB[k*NC + e + 8*ii];
      s += __shfl_xor(s, 1); s += __shfl_xor(s, 2); s += __shfl_xor(s, 4);
      float mu = s * (1.0f/128.0f);
      float vs = 0.f;
#pragma unroll
      for (int ii = 0; ii < 16; ++ii) { float dx = bufB[k*NC + e + 8*ii] - mu; vs += dx*dx; }
      vs += __shfl_xor(vs, 1); vs += __shfl_xor(vs, 2); vs += __shfl_xor(vs, 4);
      float rs = rsqrtf(vs*(1.0f/128.0f) + EPSF);
#pragma unroll
      for (int ii = 0; ii < 16; ++ii) {
        int o = e + 8*ii;
        hcur[k*NC + o] = (bufB[k*NC + o] - mu)*rs*ln2g[d*NC + o] + ln2b[d*NC + o];
      }
    }
    __syncthreads();
  }
  // maxpool over K
  if (t < NC) {
    float m = hcur[t];
    for (int k = 1; k < NK; ++k) m = fmaxf(m, hcur[k*NC + t]);
    out[(size_t)p*NC + t] = m;
  }
}

// ---------------------------------------------------------------- launcher
extern "C" void kernel_launch(void* const* d_in, const int* in_sizes, int n_in,
                              void* d_out, int out_size, void* d_ws, size_t ws_size,
                              hipStream_t stream) {
  const float* xyz    = (const float*)d_in[0];
  const float* points = (const float*)d_in[1];
  const float* w1     = (const float*)d_in[2];
  const float* g1     = (const float*)d_in[3];
  const float* b1     = (const float*)d_in[4];
  const float* w2     = (const float*)d_in[5];
  const float* g2     = (const float*)d_in[6];
  const float* b2     = (const float*)d_in[7];
  const float* w3     = (const float*)d_in[8];
  const float* g3     = (const float*)d_in[9];
  const float* b3     = (const float*)d_in[10];
  const float* wsW    = (const float*)d_in[11];
  const float* wb     = (const float*)d_in[12];
  const float* alpha  = (const float*)d_in[13];
  const float* wqkv   = (const float*)d_in[14];
  const float* wo     = (const float*)d_in[15];
  const float* ln1g   = (const float*)d_in[16];
  const float* ln1b   = (const float*)d_in[17];
  const float* ln2g   = (const float*)d_in[18];
  const float* ln2b   = (const float*)d_in[19];
  float* outp = (float*)d_out;

  float* wsf   = (float*)d_ws;
  float* gnorm = wsf;                        // 786432 f
  float* stats = wsf + 786432;               // 768 f (3 layers x 256)
  float* aff   = wsf + 787200;               // 768 f
  int*   knn   = (int*)(wsf + 787968);       // 262144 i
  float* h2    = wsf + 1050112;              // 16777216 f
  float* hX    = wsf + 17827328;             // 33554432 f (h1 first half, then h3 full)

  hipMemsetAsync(stats, 0, 768*sizeof(float), stream);
  k_fps<<<NB, 1024, 0, stream>>>(xyz, outp);
  k_knn<<<NPTS, 256, 0, stream>>>(xyz, outp, knn, gnorm);
  k_layer1<<<NM/64, 256, 0, stream>>>(points, knn, gnorm, w1, hX, stats);
  k_finalize<<<1, 128, 0, stream>>>(stats, g1, b1, aff, 64);
  k_layer<64><<<NM/64, 256, 0, stream>>>(hX, aff, w2, h2, stats + 256);
  k_finalize<<<1, 128, 0, stream>>>(stats + 256, g2, b2, aff + 256, 64);
  k_layer<128><<<NM/64, 256, 0, stream>>>(h2, aff + 256, w3, hX, stats + 512);
  k_finalize<<<1, 128, 0, stream>>>(stats + 512, g3, b3, aff + 512, 128);
  k_group<<<NPTS, 256, 0, stream>>>(hX, aff + 512, gnorm, wsW, wb, alpha, wqkv, wo,
                                    ln1g, ln1b, ln2g, ln2b, outp + (size_t)NB*NS*3);
}

// Round 2
// 4081.403 us; speedup vs baseline: 3.8014x; 3.8014x over previous
//
#include <hip/hip_runtime.h>
#include <math.h>

#define NB 8
#define NP 4096
#define NCIN 64
#define NS 1024
#define NK 32
#define NC 128
#define NJ 5
#define NDEPTH 2
#define NH 4
#define NPTS (NB*NS)       /* 8192 groups */
#define NM (NPTS*NK)       /* 262144 rows */
#define EPSF 1e-5f

typedef float f32x4 __attribute__((ext_vector_type(4)));
typedef short bf16x8 __attribute__((ext_vector_type(8)));
typedef unsigned short ushort_t;

#define MFMA(a,b,c) __builtin_amdgcn_mfma_f32_16x16x32_bf16(a,b,c,0,0,0)

__device__ __forceinline__ ushort_t f2b(float f) {
  unsigned int u = __float_as_uint(f);
  u = (u + 0x7fffu + ((u >> 16) & 1u)) >> 16;
  return (ushort_t)u;
}

// ---------------------------------------------------------------- FPS
__global__ __launch_bounds__(1024) void k_fps(const float* __restrict__ xyz,
                                              float* __restrict__ newxyz) {
  const int b = blockIdx.x;
  const int t = threadIdx.x;
  const float* X = xyz + (size_t)b * NP * 3;
  float px[4], py[4], pz[4], dist[4];
#pragma unroll
  for (int i = 0; i < 4; ++i) {
    int n = t + 1024 * i;
    px[i] = X[3*n+0]; py[i] = X[3*n+1]; pz[i] = X[3*n+2];
    dist[i] = 1e10f;
  }
  __shared__ float cen[4];
  __shared__ float wv[16];
  __shared__ int   wi[16];
  __shared__ int   sfar;
  int far = 0;
  for (int s = 0; s < NS; ++s) {
    if (t == 0) {
      float cx = X[3*far+0], cy = X[3*far+1], cz = X[3*far+2];
      cen[0]=cx; cen[1]=cy; cen[2]=cz;
      float* o = newxyz + ((size_t)b*NS + s)*3;
      o[0]=cx; o[1]=cy; o[2]=cz;
    }
    __syncthreads();
    float cx=cen[0], cy=cen[1], cz=cen[2];
    float bv = -1.0f; int bi = 0x7fffffff;
#pragma unroll
    for (int i = 0; i < 4; ++i) {
      float dx=px[i]-cx, dy=py[i]-cy, dz=pz[i]-cz;
      float d = dx*dx + dy*dy + dz*dz;
      float nd = fminf(dist[i], d);
      dist[i] = nd;
      if (nd > bv) { bv = nd; bi = t + 1024*i; }
    }
#pragma unroll
    for (int off = 32; off; off >>= 1) {
      float ov = __shfl_xor(bv, off);
      int   oi = __shfl_xor(bi, off);
      if (ov > bv || (ov == bv && oi < bi)) { bv = ov; bi = oi; }
    }
    if ((t & 63) == 0) { wv[t>>6] = bv; wi[t>>6] = bi; }
    __syncthreads();
    if (t == 0) {
      for (int w = 1; w < 16; ++w)
        if (wv[w] > bv || (wv[w] == bv && wi[w] < bi)) { bv = wv[w]; bi = wi[w]; }
      sfar = bi;
    }
    __syncthreads();
    far = sfar;
  }
}

// ---------------------------------------------------------------- KNN
__global__ __launch_bounds__(256) void k_knn(const float* __restrict__ xyz,
                                             const float* __restrict__ newxyz,
                                             int* __restrict__ knn_idx,
                                             float* __restrict__ gnorm) {
  const int p = blockIdx.x;
  const int b = p >> 10;
  const int t = threadIdx.x;
  const float* X = xyz + (size_t)b * NP * 3;
  __shared__ float d2[NP];
  __shared__ float rwv[4];
  __shared__ int   rwi[4];
  float cx = newxyz[3*p+0], cy = newxyz[3*p+1], cz = newxyz[3*p+2];
  float sc = cx*cx + cy*cy + cz*cz;
  for (int n = t; n < NP; n += 256) {
    float x = X[3*n+0], y = X[3*n+1], z = X[3*n+2];
    float sx = x*x + y*y + z*z;
    float dot = cx*x + cy*y + cz*z;
    d2[n] = sc + sx - 2.0f*dot;
  }
  __syncthreads();
  for (int it = 0; it < NK; ++it) {
    float bv = 3.0e38f; int bi = 0x7fffffff;
    for (int n = t; n < NP; n += 256) {
      float v = d2[n];
      if (v < bv) { bv = v; bi = n; }
    }
#pragma unroll
    for (int off = 32; off; off >>= 1) {
      float ov = __shfl_xor(bv, off);
      int   oi = __shfl_xor(bi, off);
      if (ov < bv || (ov == bv && oi < bi)) { bv = ov; bi = oi; }
    }
    if ((t & 63) == 0) { rwv[t>>6] = bv; rwi[t>>6] = bi; }
    __syncthreads();
    if (t == 0) {
      for (int w = 1; w < 4; ++w)
        if (rwv[w] < bv || (rwv[w] == bv && rwi[w] < bi)) { bv = rwv[w]; bi = rwi[w]; }
      d2[bi] = 3.3e38f;
      knn_idx[p*NK + it] = bi;
      float* g = gnorm + ((size_t)p*NK + it)*3;
      g[0] = X[3*bi+0] - cx;
      g[1] = X[3*bi+1] - cy;
      g[2] = X[3*bi+2] - cz;
    }
    __syncthreads();
  }
}

// ---------------------------------------------------------------- MLP layer 1
__global__ __launch_bounds__(256) void k_layer1(const float* __restrict__ points,
                                                const int* __restrict__ knn_idx,
                                                const float* __restrict__ gnorm,
                                                const float* __restrict__ w1,
                                                float* __restrict__ y,
                                                float* __restrict__ stats) {
  const int r0 = blockIdx.x * 64;
  const int t = threadIdx.x;
  __shared__ float Xs[64][69];
  __shared__ float Ws[64][69];
  __shared__ int nid[64];
  __shared__ float ps[4][64], pss[4][64];
  if (t < 64) nid[t] = knn_idx[r0 + t];
  __syncthreads();
  for (int idx = t; idx < 64*67; idx += 256) {
    int r = idx / 67, c = idx % 67;
    int row = r0 + r;
    float v;
    if (c < 3) v = gnorm[(size_t)row*3 + c];
    else {
      int bb = row >> 15;
      int n = nid[r];
      v = points[((size_t)bb*NP + n)*NCIN + (c-3)];
    }
    Xs[r][c] = v;
  }
  for (int idx = t; idx < 64*67; idx += 256) {
    int o = idx / 67, c = idx % 67;
    Ws[o][c] = w1[idx];
  }
  __syncthreads();
  const int col = t & 63;
  const int rb  = t >> 6;
  float s1 = 0.f, s2 = 0.f;
  for (int i = 0; i < 16; ++i) {
    int r = rb + 4*i;
    float acc = 0.f;
#pragma unroll
    for (int c = 0; c < 67; ++c) acc += Xs[r][c] * Ws[col][c];
    y[(size_t)(r0 + r)*64 + col] = acc;
    s1 += acc; s2 += acc*acc;
  }
  ps[rb][col] = s1; pss[rb][col] = s2;
  __syncthreads();
  if (t < 64) {
    float a = ps[0][t]+ps[1][t]+ps[2][t]+ps[3][t];
    float q = pss[0][t]+pss[1][t]+pss[2][t]+pss[3][t];
    atomicAdd(&stats[t], a);
    atomicAdd(&stats[64 + t], q);
  }
}

// ---------------------------------------------------------------- MLP layers 2/3
template <int COUT>
__global__ __launch_bounds__(256) void k_layer(const float* __restrict__ xin,
                                               const float* __restrict__ aff,
                                               const float* __restrict__ w,
                                               float* __restrict__ y,
                                               float* __restrict__ stats) {
  const int r0 = blockIdx.x * 64;
  const int t = threadIdx.x;
  __shared__ float Xs[64][65];
  __shared__ float Ws[COUT][65];
  __shared__ float sa[64], sb[64];
  constexpr int NTR = 256 / COUT;
  __shared__ float ps[NTR][COUT], pss[NTR][COUT];
  if (t < 64) { sa[t] = aff[t]; sb[t] = aff[64 + t]; }
  __syncthreads();
  for (int idx = t; idx < 64*64; idx += 256) {
    int r = idx >> 6, c = idx & 63;
    float v = xin[(size_t)r0*64 + idx];
    Xs[r][c] = fmaxf(sa[c]*v + sb[c], 0.0f);
  }
  for (int idx = t; idx < COUT*64; idx += 256) {
    int o = idx >> 6, c = idx & 63;
    Ws[o][c] = w[idx];
  }
  __syncthreads();
  const int col = t & (COUT-1);
  const int rb  = t / COUT;
  float s1 = 0.f, s2 = 0.f;
  for (int i = 0; i < 64/NTR; ++i) {
    int r = rb + NTR*i;
    float acc = 0.f;
#pragma unroll
    for (int c = 0; c < 64; ++c) acc += Xs[r][c] * Ws[col][c];
    y[(size_t)(r0 + r)*COUT + col] = acc;
    s1 += acc; s2 += acc*acc;
  }
  ps[rb][col] = s1; pss[rb][col] = s2;
  __syncthreads();
  if (t < COUT) {
    float a = 0.f, q = 0.f;
    for (int n = 0; n < NTR; ++n) { a += ps[n][t]; q += pss[n][t]; }
    atomicAdd(&stats[t], a);
    atomicAdd(&stats[COUT + t], q);
  }
}

// ---------------------------------------------------------------- BN stats -> affine
__global__ void k_finalize(const float* __restrict__ stats, const float* __restrict__ g,
                           const float* __restrict__ b, float* __restrict__ aff, int cout) {
  int t = threadIdx.x;
  if (t < cout) {
    const float inv = 1.0f / (float)NM;
    float m = stats[t] * inv;
    float var = stats[cout + t] * inv - m*m;
    float a = g[t] * rsqrtf(var + EPSF);
    aff[t] = a;
    aff[cout + t] = b[t] - m * a;
  }
}

// ---------------------------------------------------------------- pack weights to bf16 MFMA B-fragment layout
// layout per matrix (K x N, row-major src[k*N+n]): tile (tk,tn), 512 elems:
//   packed[((tk*NTN+tn)*64 + lane)*8 + j] = src[(tk*32+(lane>>4)*8+j)*N + tn*16+(lane&15)]
__global__ __launch_bounds__(256) void k_pack(const float* __restrict__ ws,
                                              const float* __restrict__ wqkv,
                                              const float* __restrict__ wo,
                                              ushort_t* __restrict__ wpk) {
  int gid = blockIdx.x*256 + threadIdx.x;    // < 294912
  const float* src; int N_; int rem;
  if (gid < 163840)      { int mat = gid >> 14; rem = gid & 16383; src = ws  + (size_t)mat*16384; N_ = 128; }
  else if (gid < 262144) { int g2 = gid - 163840; int d = g2/49152; rem = g2 - d*49152; src = wqkv + (size_t)d*49152; N_ = 384; }
  else                   { int g3 = gid - 262144; int d = g3 >> 14; rem = g3 & 16383;  src = wo  + (size_t)d*16384; N_ = 128; }
  int NTN = N_ >> 4;
  int tile = rem >> 9, r = rem & 511;
  int tk = tile / NTN, tn = tile % NTN;
  int lane2 = r >> 3, jj = r & 7;
  int k = tk*32 + (lane2 >> 4)*8 + jj;
  int n = tn*16 + (lane2 & 15);
  wpk[gid] = f2b(src[(size_t)k*N_ + n]);
}

// ---------------------------------------------------------------- fused per-group (MFMA version)
__global__ __launch_bounds__(256) void k_group(
    const float* __restrict__ h3, const float* __restrict__ aff3,
    const float* __restrict__ gnorm,
    const ushort_t* __restrict__ wpk,
    const float* __restrict__ wb, const float* __restrict__ alpha,
    const float* __restrict__ ln1g, const float* __restrict__ ln1b,
    const float* __restrict__ ln2g, const float* __restrict__ ln2b,
    float* __restrict__ out) {
  const int p = blockIdx.x;
  const int t = threadIdx.x;
  const int lane = t & 63;
  const int w = t >> 6;

  __shared__ __align__(16) float   hcurS[NK*NC];     // 16 KB fp32 activations
  __shared__ __align__(16) ushort_t hbS[NK*NC];      // 8 KB bf16 mirror, XOR-swizzled rows
  __shared__ __align__(16) float   workS[NK*NC];     // 16 KB scratch: L/acc/accN/T, u, o
  __shared__ __align__(16) ushort_t attnS[5120];     // 10 KB: Hj col-major [c][40] OR q/Kc/vT/att [32][40] each
  __shared__ __align__(16) float   scoresS[1056];    // scores [32][33]; init: px[0:96], dinv[96:128]
  __shared__ __align__(16) ushort_t psisS[5*32*40];  // 12.5 KB psi_j row-major [32][40] bf16

  // ---- init: px, pf -> hcur/hb
  if (t < 96) scoresS[t] = gnorm[(size_t)p*96 + t];
  const float* h3p = h3 + (size_t)p*4096;
#pragma unroll
  for (int i = 0; i < 16; ++i) {
    int idx = t + 256*i;
    int c = idx & 127, row = idx >> 7;
    float v = fmaxf(aff3[c]*h3p[idx] + aff3[128+c], 0.f);
    hcurS[idx] = v;
    int ha = ((row << 8) + (c << 1)) ^ ((row & 7) << 4);
    hbS[ha >> 1] = f2b(v);
  }
  __syncthreads();
  // ---- dd -> workS[1024:2048)
  for (int i = t; i < 1024; i += 256) {
    int k = i >> 5, l = i & 31;
    float dx = scoresS[k*3]  -scoresS[l*3];
    float dy = scoresS[k*3+1]-scoresS[l*3+1];
    float dz = scoresS[k*3+2]-scoresS[l*3+2];
    workS[1024+i] = dx*dx + dy*dy + dz*dz;
  }
  __syncthreads();
  // ---- sigma
  float part = 0.f;
  for (int i = t; i < 1024; i += 256) part += sqrtf(workS[1024+i] + 1e-12f);
#pragma unroll
  for (int off = 32; off; off >>= 1) part += __shfl_xor(part, off);
  if (lane == 0) workS[2048 + w] = part;
  __syncthreads();
  if (t == 0) {
    float sg = (workS[2048]+workS[2049]+workS[2050]+workS[2051]) * (1.0f/1024.0f);
    workS[2052] = 2.0f*sg*sg + 1e-12f;
  }
  __syncthreads();
  const float denom = workS[2052];
  for (int i = t; i < 1024; i += 256) workS[1024+i] = expf(-workS[1024+i] / denom);  // A
  __syncthreads();
  if (t < 32) {
    float s = 0.f;
    for (int l = 0; l < 32; ++l) s += workS[1024 + t*32 + l];
    scoresS[96 + t] = rsqrtf(s + 1e-12f);    // dinv
  }
  __syncthreads();
  for (int i = t; i < 1024; i += 256) {      // L -> workS[0:1024)
    int k = i >> 5, l = i & 31;
    float v = -(scoresS[96+k] * workS[1024+i] * scoresS[96+l]);
    if (k == l) v += 1.0f;
    workS[i] = v;
  }
  __syncthreads();

  // ---- psis (once; independent of depth): T_j = I + sum_{m=1..4} M^m/m!, M = sj*L
  for (int j = 0; j < NJ; ++j) {
    const float sj = -0.05f * (float)(1 << j);
    for (int i = t; i < 1024; i += 256) {
      float m = sj * workS[i];
      workS[1024+i] = m;                                        // acc = M
      workS[3072+i] = (((i>>5) == (i&31)) ? 1.0f : 0.0f) + m;   // T = I + M
    }
    __syncthreads();
    int accOff = 1024, accNOff = 2048;
    for (int m = 2; m <= 4; ++m) {
      const float s_inv = sj / (float)m;
      for (int i = t; i < 1024; i += 256) {
        int k = i >> 5, l = i & 31;
        float a = 0.f;
#pragma unroll
        for (int q = 0; q < 32; ++q) a += workS[accOff + k*32 + q] * workS[q*32 + l];
        a *= s_inv;
        workS[accNOff + i] = a;
        workS[3072 + i] += a;
      }
      int tmp = accOff; accOff = accNOff; accNOff = tmp;
      __syncthreads();
    }
    for (int i = t; i < 1024; i += 256)
      psisS[j*1280 + (i>>5)*40 + (i&31)] = f2b(workS[3072+i]);
    __syncthreads();
  }

  // ---- depth loop
  for (int d = 0; d < NDEPTH; ++d) {
    // ===== mix (registers) = sum_j alpha_j * psi_j @ (hcur @ Ws_j)
    f32x4 m00 = {0.f,0.f,0.f,0.f}, m01 = m00, m10 = m00, m11 = m00;
    for (int j = 0; j < NJ; ++j) {
      __syncthreads();                      // attnS free for reuse
      const ushort_t* Wp = wpk + (size_t)(d*NJ + j)*16384;
      const float alj = alpha[d*NJ + j];
      // Hj = hcur @ Ws_j  (scaled by alpha), store col-major bf16 attnS[c*40+row]
#pragma unroll
      for (int tni = 0; tni < 2; ++tni) {
        int tn = 2*w + tni;
        f32x4 acc0 = {0.f,0.f,0.f,0.f}, acc1 = acc0;
#pragma unroll
        for (int tk = 0; tk < 4; ++tk) {
          bf16x8 b = *(const bf16x8*)(Wp + ((tk*8 + tn) << 9) + (lane << 3));
          int row0 = lane & 15;
          int ba0 = (((row0) << 8) + (tk << 6) + ((lane >> 4) << 4)) ^ ((row0 & 7) << 4);
          bf16x8 a0 = *(const bf16x8*)((const char*)hbS + ba0);
          acc0 = MFMA(a0, b, acc0);
          int row1 = 16 + (lane & 15);
          int ba1 = (((row1) << 8) + (tk << 6) + ((lane >> 4) << 4)) ^ ((row1 & 7) << 4);
          bf16x8 a1 = *(const bf16x8*)((const char*)hbS + ba1);
          acc1 = MFMA(a1, b, acc1);
        }
        int c = tn*16 + (lane & 15);
        int rbase = (lane >> 4) * 4;
#pragma unroll
        for (int r = 0; r < 4; ++r) {
          attnS[c*40 + rbase + r]      = f2b(alj * acc0[r]);
          attnS[c*40 + 16 + rbase + r] = f2b(alj * acc1[r]);
        }
      }
      __syncthreads();
      // mix += psi_j @ Hj
      {
        const char* psj = (const char*)(psisS + j*1280);
        int koff = (lane >> 4) << 4;
        bf16x8 pa0 = *(const bf16x8*)(psj + (lane & 15)*80 + koff);
        bf16x8 pa1 = *(const bf16x8*)(psj + (16 + (lane & 15))*80 + koff);
        int n0 = 2*w*16 + (lane & 15);
        bf16x8 hb0 = *(const bf16x8*)((const char*)attnS + n0*80 + koff);
        bf16x8 hb1 = *(const bf16x8*)((const char*)attnS + (n0 + 16)*80 + koff);
        m00 = MFMA(pa0, hb0, m00);
        m01 = MFMA(pa0, hb1, m01);
        m10 = MFMA(pa1, hb0, m10);
        m11 = MFMA(pa1, hb1, m11);
      }
    }
    __syncthreads();
    // ===== u = hcur + relu(mix + wb) -> workS
    {
      int c0 = 32*w + (lane & 15);
      int c1 = c0 + 16;
      int r0 = (lane >> 4) * 4;
      float wb0 = wb[d*NC + c0], wb1 = wb[d*NC + c1];
#pragma unroll
      for (int r = 0; r < 4; ++r) {
        int row0 = r0 + r, row1 = 16 + r0 + r;
        workS[row0*NC + c0] = hcurS[row0*NC + c0] + fmaxf(m00[r] + wb0, 0.f);
        workS[row0*NC + c1] = hcurS[row0*NC + c1] + fmaxf(m01[r] + wb1, 0.f);
        workS[row1*NC + c0] = hcurS[row1*NC + c0] + fmaxf(m10[r] + wb0, 0.f);
        workS[row1*NC + c1] = hcurS[row1*NC + c1] + fmaxf(m11[r] + wb1, 0.f);
      }
    }
    __syncthreads();
    // ===== LN1: workS -> hcurS + hbS
    {
      const int k = t >> 3, e = t & 7;
      float s = 0.f;
#pragma unroll
      for (int ii = 0; ii < 16; ++ii) s += workS[k*NC + e + 8*ii];
      s += __shfl_xor(s,1); s += __shfl_xor(s,2); s += __shfl_xor(s,4);
      float mu = s * (1.0f/128.0f);
      float vs = 0.f;
#pragma unroll
      for (int ii = 0; ii < 16; ++ii) { float dx = workS[k*NC + e + 8*ii] - mu; vs += dx*dx; }
      vs += __shfl_xor(vs,1); vs += __shfl_xor(vs,2); vs += __shfl_xor(vs,4);
      float rs = rsqrtf(vs*(1.0f/128.0f) + EPSF);
#pragma unroll
      for (int ii = 0; ii < 16; ++ii) {
        int o = e + 8*ii;
        float hv = (workS[k*NC + o] - mu)*rs*ln1g[d*NC + o] + ln1b[d*NC + o];
        hcurS[k*NC + o] = hv;
        int ha = ((k << 8) + (o << 1)) ^ ((k & 7) << 4);
        hbS[ha >> 1] = f2b(hv);
      }
    }
    __syncthreads();
    // ===== attention, per head; o -> workS
    const ushort_t* Wq = wpk + 163840 + (size_t)d*49152;
    for (int h = 0; h < NH; ++h) {
      // qkv: 12 tiles (3 comp x 2m x 2n); wave w does tiles w, w+4, w+8
#pragma unroll
      for (int ti = 0; ti < 3; ++ti) {
        int tile = w + ti*4;
        int comp = tile >> 2, mi = (tile >> 1) & 1, ni = tile & 1;
        int tn = comp*8 + h*2 + ni;
        f32x4 acc = {0.f,0.f,0.f,0.f};
#pragma unroll
        for (int tk = 0; tk < 4; ++tk) {
          bf16x8 b = *(const bf16x8*)(Wq + ((tk*24 + tn) << 9) + (lane << 3));
          int row = mi*16 + (lane & 15);
          int ba = ((row << 8) + (tk << 6) + ((lane >> 4) << 4)) ^ ((row & 7) << 4);
          bf16x8 a = *(const bf16x8*)((const char*)hbS + ba);
          acc = MFMA(a, b, acc);
        }
        int ddl = ni*16 + (lane & 15);
        int rb2 = mi*16 + (lane >> 4)*4;
        if (comp == 0) {          // q row-major [32][40]
#pragma unroll
          for (int r = 0; r < 4; ++r) attnS[(rb2 + r)*40 + ddl] = f2b(acc[r]);
        } else if (comp == 1) {   // K row-major [32][40] (B for scores: contraction dd contiguous)
#pragma unroll
          for (int r = 0; r < 4; ++r) attnS[1280 + (rb2 + r)*40 + ddl] = f2b(acc[r]);
        } else {                  // vT [dd][l] (B for PV: contraction l contiguous)
#pragma unroll
          for (int r = 0; r < 4; ++r) attnS[2560 + ddl*40 + rb2 + r] = f2b(acc[r]);
        }
      }
      __syncthreads();
      // scores = q @ K^T / sqrt(32): wave w -> tile (mi=w>>1, ni=w&1)
      {
        int mi = w >> 1, ni = w & 1;
        int koff = (lane >> 4) << 4;
        bf16x8 qa = *(const bf16x8*)((const char*)attnS + (mi*16 + (lane & 15))*80 + koff);
        bf16x8 kb = *(const bf16x8*)((const char*)(attnS + 1280) + (ni*16 + (lane & 15))*80 + koff);
        f32x4 sc = {0.f,0.f,0.f,0.f};
        sc = MFMA(qa, kb, sc);
        int colL = ni*16 + (lane & 15);
        int rb2 = mi*16 + (lane >> 4)*4;
#pragma unroll
        for (int r = 0; r < 4; ++r) scoresS[(rb2 + r)*33 + colL] = sc[r] * 0.17677669529663687f;
      }
      __syncthreads();
      // softmax rows (8 threads/row) -> att bf16 [32][40]
      {
        int row = t >> 3, e = t & 7;
        float v0 = scoresS[row*33 + e],      v1 = scoresS[row*33 + e + 8];
        float v2 = scoresS[row*33 + e + 16], v3 = scoresS[row*33 + e + 24];
        float mx = fmaxf(fmaxf(v0,v1), fmaxf(v2,v3));
        mx = fmaxf(mx, __shfl_xor(mx,1)); mx = fmaxf(mx, __shfl_xor(mx,2)); mx = fmaxf(mx, __shfl_xor(mx,4));
        v0 = expf(v0-mx); v1 = expf(v1-mx); v2 = expf(v2-mx); v3 = expf(v3-mx);
        float s = v0+v1+v2+v3;
        s += __shfl_xor(s,1); s += __shfl_xor(s,2); s += __shfl_xor(s,4);
        float inv = 1.0f/s;
        attnS[3840 + row*40 + e]      = f2b(v0*inv);
        attnS[3840 + row*40 + e + 8]  = f2b(v1*inv);
        attnS[3840 + row*40 + e + 16] = f2b(v2*inv);
        attnS[3840 + row*40 + e + 24] = f2b(v3*inv);
      }
      __syncthreads();
      // PV: o tile -> workS cols [h*32 .. h*32+31]
      {
        int mi = w >> 1, ni = w & 1;
        int koff = (lane >> 4) << 4;
        bf16x8 aa = *(const bf16x8*)((const char*)(attnS + 3840) + (mi*16 + (lane & 15))*80 + koff);
        bf16x8 vb = *(const bf16x8*)((const char*)(attnS + 2560) + (ni*16 + (lane & 15))*80 + koff);
        f32x4 ov = {0.f,0.f,0.f,0.f};
        ov = MFMA(aa, vb, ov);
        int col = h*32 + ni*16 + (lane & 15);
        int rb2 = mi*16 + (lane >> 4)*4;
#pragma unroll
        for (int r = 0; r < 4; ++r) workS[(rb2 + r)*NC + col] = ov[r];
      }
      __syncthreads();
    }
    // ===== o -> hbS (bf16, swizzled)
#pragma unroll
    for (int i = 0; i < 16; ++i) {
      int idx = t + 256*i;
      int row = idx >> 7, c = idx & 127;
      int ha = ((row << 8) + (c << 1)) ^ ((row & 7) << 4);
      hbS[ha >> 1] = f2b(workS[idx]);
    }
    __syncthreads();
    // ===== proj: o @ Wo; u2 = hcur + proj -> workS
    const ushort_t* Wop = wpk + 262144 + (size_t)d*16384;
#pragma unroll
    for (int tni = 0; tni < 2; ++tni) {
      int tn = 2*w + tni;
      f32x4 acc0 = {0.f,0.f,0.f,0.f}, acc1 = acc0;
#pragma unroll
      for (int tk = 0; tk < 4; ++tk) {
        bf16x8 b = *(const bf16x8*)(Wop + ((tk*8 + tn) << 9) + (lane << 3));
        int row0 = lane & 15;
        int ba0 = ((row0 << 8) + (tk << 6) + ((lane >> 4) << 4)) ^ ((row0 & 7) << 4);
        bf16x8 a0 = *(const bf16x8*)((const char*)hbS + ba0);
        acc0 = MFMA(a0, b, acc0);
        int row1 = 16 + (lane & 15);
        int ba1 = ((row1 << 8) + (tk << 6) + ((lane >> 4) << 4)) ^ ((row1 & 7) << 4);
        bf16x8 a1 = *(const bf16x8*)((const char*)hbS + ba1);
        acc1 = MFMA(a1, b, acc1);
      }
      int c = tn*16 + (lane & 15);
      int rb2 = (lane >> 4)*4;
#pragma unroll
      for (int r = 0; r < 4; ++r) {
        workS[(rb2 + r)*NC + c]        = hcurS[(rb2 + r)*NC + c]        + acc0[r];
        workS[(16 + rb2 + r)*NC + c]   = hcurS[(16 + rb2 + r)*NC + c]   + acc1[r];
      }
    }
    __syncthreads();
    // ===== LN2: workS -> hcurS + hbS
    {
      const int k = t >> 3, e = t & 7;
      float s = 0.f;
#pragma unroll
      for (int ii = 0; ii < 16; ++ii) s += workS[k*NC + e + 8*ii];
      s += __shfl_xor(s,1); s += __shfl_xor(s,2); s += __shfl_xor(s,4);
      float mu = s * (1.0f/128.0f);
      float vs = 0.f;
#pragma unroll
      for (int ii = 0; ii < 16; ++ii) { float dx = workS[k*NC + e + 8*ii] - mu; vs += dx*dx; }
      vs += __shfl_xor(vs,1); vs += __shfl_xor(vs,2); vs += __shfl_xor(vs,4);
      float rs = rsqrtf(vs*(1.0f/128.0f) + EPSF);
#pragma unroll
      for (int ii = 0; ii < 16; ++ii) {
        int o = e + 8*ii;
        float hv = (workS[k*NC + o] - mu)*rs*ln2g[d*NC + o] + ln2b[d*NC + o];
        hcurS[k*NC + o] = hv;
        int ha = ((k << 8) + (o << 1)) ^ ((k & 7) << 4);
        hbS[ha >> 1] = f2b(hv);
      }
    }
    __syncthreads();
  }
  // ---- maxpool over K
  if (t < NC) {
    float m = hcurS[t];
    for (int k = 1; k < NK; ++k) m = fmaxf(m, hcurS[k*NC + t]);
    out[(size_t)p*NC + t] = m;
  }
}

// ---------------------------------------------------------------- launcher
extern "C" void kernel_launch(void* const* d_in, const int* in_sizes, int n_in,
                              void* d_out, int out_size, void* d_ws, size_t ws_size,
                              hipStream_t stream) {
  const float* xyz    = (const float*)d_in[0];
  const float* points = (const float*)d_in[1];
  const float* w1     = (const float*)d_in[2];
  const float* g1     = (const float*)d_in[3];
  const float* b1     = (const float*)d_in[4];
  const float* w2     = (const float*)d_in[5];
  const float* g2     = (const float*)d_in[6];
  const float* b2     = (const float*)d_in[7];
  const float* w3     = (const float*)d_in[8];
  const float* g3     = (const float*)d_in[9];
  const float* b3     = (const float*)d_in[10];
  const float* wsW    = (const float*)d_in[11];
  const float* wb     = (const float*)d_in[12];
  const float* alpha  = (const float*)d_in[13];
  const float* wqkv   = (const float*)d_in[14];
  const float* wo     = (const float*)d_in[15];
  const float* ln1g   = (const float*)d_in[16];
  const float* ln1b   = (const float*)d_in[17];
  const float* ln2g   = (const float*)d_in[18];
  const float* ln2b   = (const float*)d_in[19];
  float* outp = (float*)d_out;

  float* wsf   = (float*)d_ws;
  float* gnorm = wsf;                        // 786432 f
  float* stats = wsf + 786432;               // 768 f
  float* aff   = wsf + 787200;               // 768 f
  int*   knn   = (int*)(wsf + 787968);       // 262144 i  (reused as wpk after k_layer1)
  ushort_t* wpk = (ushort_t*)(wsf + 787968); // 294912 bf16 = 589824 B (fits in knn's 1 MB)
  float* h2    = wsf + 1050112;              // 16777216 f
  float* hX    = wsf + 17827328;             // 33554432 f

  hipMemsetAsync(stats, 0, 768*sizeof(float), stream);
  k_fps<<<NB, 1024, 0, stream>>>(xyz, outp);
  k_knn<<<NPTS, 256, 0, stream>>>(xyz, outp, knn, gnorm);
  k_layer1<<<NM/64, 256, 0, stream>>>(points, knn, gnorm, w1, hX, stats);
  // knn indices consumed; overwrite region with packed bf16 weights
  k_pack<<<294912/256, 256, 0, stream>>>(wsW, wqkv, wo, wpk);
  k_finalize<<<1, 128, 0, stream>>>(stats, g1, b1, aff, 64);
  k_layer<64><<<NM/64, 256, 0, stream>>>(hX, aff, w2, h2, stats + 256);
  k_finalize<<<1, 128, 0, stream>>>(stats + 256, g2, b2, aff + 256, 64);
  k_layer<128><<<NM/64, 256, 0, stream>>>(h2, aff + 256, w3, hX, stats + 512);
  k_finalize<<<1, 128, 0, stream>>>(stats + 512, g3, b3, aff + 512, 128);
  k_group<<<NPTS, 256, 0, stream>>>(hX, aff + 512, gnorm, wpk, wb, alpha,
                                    ln1g, ln1b, ln2g, ln2b, outp + (size_t)NB*NS*3);
}

// Round 3
// 2807.963 us; speedup vs baseline: 5.5253x; 1.4535x over previous
//
#include <hip/hip_runtime.h>
#include <math.h>

#define NB 8
#define NP 4096
#define NCIN 64
#define NS 1024
#define NK 32
#define NC 128
#define NJ 5
#define NDEPTH 2
#define NH 4
#define NPTS (NB*NS)       /* 8192 groups */
#define NM (NPTS*NK)       /* 262144 rows */
#define EPSF 1e-5f

typedef float f32x4 __attribute__((ext_vector_type(4)));
typedef short bf16x8 __attribute__((ext_vector_type(8)));
typedef unsigned short ushort_t;

#define MFMA(a,b,c) __builtin_amdgcn_mfma_f32_16x16x32_bf16(a,b,c,0,0,0)

__device__ __forceinline__ ushort_t f2b(float f) {
  unsigned int u = __float_as_uint(f);
  u = (u + 0x7fffu + ((u >> 16) & 1u)) >> 16;
  return (ushort_t)u;
}

// ---------------------------------------------------------------- FPS
// 256 threads, 16 pts/lane in registers, coords staged in LDS.
// One barrier per step (parity-double-buffered reduce slots).
__global__ __launch_bounds__(256) void k_fps(const float* __restrict__ xyz,
                                             float* __restrict__ newxyz) {
  const int b = blockIdx.x;
  const int t = threadIdx.x;
  const int lane = t & 63;
  const int w = t >> 6;
  __shared__ float Xl[NP*3];          // 48 KB coord stage
  __shared__ float redV[2][4];
  __shared__ int   redI[2][4];
  const float* X = xyz + (size_t)b * NP * 3;
  for (int i = t; i < NP*3; i += 256) Xl[i] = X[i];
  __syncthreads();
  float px[16], py[16], pz[16], dist[16];
#pragma unroll
  for (int i = 0; i < 16; ++i) {
    int n = t + 256*i;
    px[i] = Xl[3*n]; py[i] = Xl[3*n+1]; pz[i] = Xl[3*n+2];
    dist[i] = 1e10f;
  }
  int far = 0;
  for (int s = 0; s < NS; ++s) {
    // centroid: same-address LDS broadcast (far uniform across block)
    float cx = Xl[3*far], cy = Xl[3*far+1], cz = Xl[3*far+2];
    if (t == 0) {
      float* o = newxyz + ((size_t)b*NS + s)*3;
      o[0] = cx; o[1] = cy; o[2] = cz;
    }
    float bv = -1.0f; int bi = 0x7fffffff;
#pragma unroll
    for (int i = 0; i < 16; ++i) {
      float dx = px[i]-cx, dy = py[i]-cy, dz = pz[i]-cz;
      float d = fmaf(dx,dx, fmaf(dy,dy, dz*dz));
      float nd = fminf(dist[i], d);
      dist[i] = nd;
      if (nd > bv) { bv = nd; bi = t + 256*i; }   // ascending n: strict > keeps lowest idx
    }
#pragma unroll
    for (int off = 32; off; off >>= 1) {
      float ov = __shfl_xor(bv, off);
      int   oi = __shfl_xor(bi, off);
      if (ov > bv || (ov == bv && oi < bi)) { bv = ov; bi = oi; }
    }
    if (lane == 0) { redV[s&1][w] = bv; redI[s&1][w] = bi; }
    __syncthreads();
    // every thread reduces the 4 wave results itself -> no 2nd barrier
    bv = redV[s&1][0]; bi = redI[s&1][0];
#pragma unroll
    for (int ww = 1; ww < 4; ++ww) {
      float ov = redV[s&1][ww]; int oi = redI[s&1][ww];
      if (ov > bv || (ov == bv && oi < bi)) { bv = ov; bi = oi; }
    }
    far = bi;
  }
}

// ---------------------------------------------------------------- KNN: one wave per query, zero barriers
__global__ __launch_bounds__(64) void k_knn(const float* __restrict__ xyz,
                                            const float* __restrict__ newxyz,
                                            int* __restrict__ knn_idx,
                                            float* __restrict__ gnorm) {
  const int p = blockIdx.x;
  const int b = p >> 10;
  const int lane = threadIdx.x;
  const float* X = xyz + (size_t)b * NP * 3;
  __shared__ float d2[NP];            // 16 KB -> 10 waves/CU
  float cx = newxyz[3*p], cy = newxyz[3*p+1], cz = newxyz[3*p+2];
  float sc = cx*cx + cy*cy + cz*cz;
#pragma unroll 4
  for (int i = 0; i < NP/64; ++i) {
    int n = lane + 64*i;              // bank-conflict-free (2 lanes/bank)
    float x = X[3*n], y = X[3*n+1], z = X[3*n+2];
    float sx = x*x + y*y + z*z;
    float dot = cx*x + cy*y + cz*z;
    d2[n] = sc + sx - 2.0f*dot;       // same formula/rounding as reference
  }
  for (int it = 0; it < NK; ++it) {
    float bv = 3.0e38f; int bi = 0x7fffffff;
#pragma unroll 8
    for (int i = 0; i < NP/64; ++i) {
      int n = lane + 64*i;            // ascending n per lane
      float v = d2[n];
      if (v < bv) { bv = v; bi = n; }
    }
#pragma unroll
    for (int off = 32; off; off >>= 1) {
      float ov = __shfl_xor(bv, off);
      int   oi = __shfl_xor(bi, off);
      if (ov < bv || (ov == bv && oi < bi)) { bv = ov; bi = oi; }
    }
    if (lane == 0) {
      d2[bi] = 3.3e38f;               // wave-synchronous; visible next iter
      knn_idx[p*NK + it] = bi;
      float* g = gnorm + ((size_t)p*NK + it)*3;
      g[0] = X[3*bi]   - cx;
      g[1] = X[3*bi+1] - cy;
      g[2] = X[3*bi+2] - cz;
    }
  }
}

// ---------------------------------------------------------------- MLP layer 1
__global__ __launch_bounds__(256) void k_layer1(const float* __restrict__ points,
                                                const int* __restrict__ knn_idx,
                                                const float* __restrict__ gnorm,
                                                const float* __restrict__ w1,
                                                float* __restrict__ y,
                                                float* __restrict__ stats) {
  const int r0 = blockIdx.x * 64;
  const int t = threadIdx.x;
  __shared__ float Xs[64][69];
  __shared__ float Ws[64][69];
  __shared__ int nid[64];
  __shared__ float ps[4][64], pss[4][64];
  if (t < 64) nid[t] = knn_idx[r0 + t];
  __syncthreads();
  for (int idx = t; idx < 64*67; idx += 256) {
    int r = idx / 67, c = idx % 67;
    int row = r0 + r;
    float v;
    if (c < 3) v = gnorm[(size_t)row*3 + c];
    else {
      int bb = row >> 15;
      int n = nid[r];
      v = points[((size_t)bb*NP + n)*NCIN + (c-3)];
    }
    Xs[r][c] = v;
  }
  for (int idx = t; idx < 64*67; idx += 256) {
    int o = idx / 67, c = idx % 67;
    Ws[o][c] = w1[idx];
  }
  __syncthreads();
  const int col = t & 63;
  const int rb  = t >> 6;
  float s1 = 0.f, s2 = 0.f;
  for (int i = 0; i < 16; ++i) {
    int r = rb + 4*i;
    float acc = 0.f;
#pragma unroll
    for (int c = 0; c < 67; ++c) acc += Xs[r][c] * Ws[col][c];
    y[(size_t)(r0 + r)*64 + col] = acc;
    s1 += acc; s2 += acc*acc;
  }
  ps[rb][col] = s1; pss[rb][col] = s2;
  __syncthreads();
  if (t < 64) {
    float a = ps[0][t]+ps[1][t]+ps[2][t]+ps[3][t];
    float q = pss[0][t]+pss[1][t]+pss[2][t]+pss[3][t];
    atomicAdd(&stats[t], a);
    atomicAdd(&stats[64 + t], q);
  }
}

// ---------------------------------------------------------------- MLP layers 2/3
template <int COUT>
__global__ __launch_bounds__(256) void k_layer(const float* __restrict__ xin,
                                               const float* __restrict__ aff,
                                               const float* __restrict__ w,
                                               float* __restrict__ y,
                                               float* __restrict__ stats) {
  const int r0 = blockIdx.x * 64;
  const int t = threadIdx.x;
  __shared__ float Xs[64][65];
  __shared__ float Ws[COUT][65];
  __shared__ float sa[64], sb[64];
  constexpr int NTR = 256 / COUT;
  __shared__ float ps[NTR][COUT], pss[NTR][COUT];
  if (t < 64) { sa[t] = aff[t]; sb[t] = aff[64 + t]; }
  __syncthreads();
  for (int idx = t; idx < 64*64; idx += 256) {
    int r = idx >> 6, c = idx & 63;
    float v = xin[(size_t)r0*64 + idx];
    Xs[r][c] = fmaxf(sa[c]*v + sb[c], 0.0f);
  }
  for (int idx = t; idx < COUT*64; idx += 256) {
    int o = idx >> 6, c = idx & 63;
    Ws[o][c] = w[idx];
  }
  __syncthreads();
  const int col = t & (COUT-1);
  const int rb  = t / COUT;
  float s1 = 0.f, s2 = 0.f;
  for (int i = 0; i < 64/NTR; ++i) {
    int r = rb + NTR*i;
    float acc = 0.f;
#pragma unroll
    for (int c = 0; c < 64; ++c) acc += Xs[r][c] * Ws[col][c];
    y[(size_t)(r0 + r)*COUT + col] = acc;
    s1 += acc; s2 += acc*acc;
  }
  ps[rb][col] = s1; pss[rb][col] = s2;
  __syncthreads();
  if (t < COUT) {
    float a = 0.f, q = 0.f;
    for (int n = 0; n < NTR; ++n) { a += ps[n][t]; q += pss[n][t]; }
    atomicAdd(&stats[t], a);
    atomicAdd(&stats[COUT + t], q);
  }
}

// ---------------------------------------------------------------- BN stats -> affine
__global__ void k_finalize(const float* __restrict__ stats, const float* __restrict__ g,
                           const float* __restrict__ b, float* __restrict__ aff, int cout) {
  int t = threadIdx.x;
  if (t < cout) {
    const float inv = 1.0f / (float)NM;
    float m = stats[t] * inv;
    float var = stats[cout + t] * inv - m*m;
    float a = g[t] * rsqrtf(var + EPSF);
    aff[t] = a;
    aff[cout + t] = b[t] - m * a;
  }
}

// ---------------------------------------------------------------- pack weights to bf16 MFMA B-fragment layout
__global__ __launch_bounds__(256) void k_pack(const float* __restrict__ ws,
                                              const float* __restrict__ wqkv,
                                              const float* __restrict__ wo,
                                              ushort_t* __restrict__ wpk) {
  int gid = blockIdx.x*256 + threadIdx.x;    // < 294912
  const float* src; int N_; int rem;
  if (gid < 163840)      { int mat = gid >> 14; rem = gid & 16383; src = ws  + (size_t)mat*16384; N_ = 128; }
  else if (gid < 262144) { int g2 = gid - 163840; int d = g2/49152; rem = g2 - d*49152; src = wqkv + (size_t)d*49152; N_ = 384; }
  else                   { int g3 = gid - 262144; int d = g3 >> 14; rem = g3 & 16383;  src = wo  + (size_t)d*16384; N_ = 128; }
  int NTN = N_ >> 4;
  int tile = rem >> 9, r = rem & 511;
  int tk = tile / NTN, tn = tile % NTN;
  int lane2 = r >> 3, jj = r & 7;
  int k = tk*32 + (lane2 >> 4)*8 + jj;
  int n = tn*16 + (lane2 & 15);
  wpk[gid] = f2b(src[(size_t)k*N_ + n]);
}

// ---------------------------------------------------------------- fused per-group (MFMA version)
__global__ __launch_bounds__(256) void k_group(
    const float* __restrict__ h3, const float* __restrict__ aff3,
    const float* __restrict__ gnorm,
    const ushort_t* __restrict__ wpk,
    const float* __restrict__ wb, const float* __restrict__ alpha,
    const float* __restrict__ ln1g, const float* __restrict__ ln1b,
    const float* __restrict__ ln2g, const float* __restrict__ ln2b,
    float* __restrict__ out) {
  const int p = blockIdx.x;
  const int t = threadIdx.x;
  const int lane = t & 63;
  const int w = t >> 6;

  __shared__ __align__(16) float   hcurS[NK*NC];     // 16 KB fp32 activations
  __shared__ __align__(16) ushort_t hbS[NK*NC];      // 8 KB bf16 mirror, XOR-swizzled rows
  __shared__ __align__(16) float   workS[NK*NC];     // 16 KB scratch
  __shared__ __align__(16) ushort_t attnS[5120];     // 10 KB
  __shared__ __align__(16) float   scoresS[1056];    // scores [32][33]; init: px, dinv
  __shared__ __align__(16) ushort_t psisS[5*32*40];  // 12.5 KB

  // ---- init: px, pf -> hcur/hb
  if (t < 96) scoresS[t] = gnorm[(size_t)p*96 + t];
  const float* h3p = h3 + (size_t)p*4096;
#pragma unroll
  for (int i = 0; i < 16; ++i) {
    int idx = t + 256*i;
    int c = idx & 127, row = idx >> 7;
    float v = fmaxf(aff3[c]*h3p[idx] + aff3[128+c], 0.f);
    hcurS[idx] = v;
    int ha = ((row << 8) + (c << 1)) ^ ((row & 7) << 4);
    hbS[ha >> 1] = f2b(v);
  }
  __syncthreads();
  // ---- dd -> workS[1024:2048)
  for (int i = t; i < 1024; i += 256) {
    int k = i >> 5, l = i & 31;
    float dx = scoresS[k*3]  -scoresS[l*3];
    float dy = scoresS[k*3+1]-scoresS[l*3+1];
    float dz = scoresS[k*3+2]-scoresS[l*3+2];
    workS[1024+i] = dx*dx + dy*dy + dz*dz;
  }
  __syncthreads();
  // ---- sigma
  float part = 0.f;
  for (int i = t; i < 1024; i += 256) part += sqrtf(workS[1024+i] + 1e-12f);
#pragma unroll
  for (int off = 32; off; off >>= 1) part += __shfl_xor(part, off);
  if (lane == 0) workS[2048 + w] = part;
  __syncthreads();
  if (t == 0) {
    float sg = (workS[2048]+workS[2049]+workS[2050]+workS[2051]) * (1.0f/1024.0f);
    workS[2052] = 2.0f*sg*sg + 1e-12f;
  }
  __syncthreads();
  const float denom = workS[2052];
  for (int i = t; i < 1024; i += 256) workS[1024+i] = expf(-workS[1024+i] / denom);  // A
  __syncthreads();
  if (t < 32) {
    float s = 0.f;
    for (int l = 0; l < 32; ++l) s += workS[1024 + t*32 + l];
    scoresS[96 + t] = rsqrtf(s + 1e-12f);    // dinv
  }
  __syncthreads();
  for (int i = t; i < 1024; i += 256) {      // L -> workS[0:1024)
    int k = i >> 5, l = i & 31;
    float v = -(scoresS[96+k] * workS[1024+i] * scoresS[96+l]);
    if (k == l) v += 1.0f;
    workS[i] = v;
  }
  __syncthreads();

  // ---- psis (once): T_j = I + sum_{m=1..4} M^m/m!, M = sj*L
  for (int j = 0; j < NJ; ++j) {
    const float sj = -0.05f * (float)(1 << j);
    for (int i = t; i < 1024; i += 256) {
      float m = sj * workS[i];
      workS[1024+i] = m;
      workS[3072+i] = (((i>>5) == (i&31)) ? 1.0f : 0.0f) + m;
    }
    __syncthreads();
    int accOff = 1024, accNOff = 2048;
    for (int m = 2; m <= 4; ++m) {
      const float s_inv = sj / (float)m;
      for (int i = t; i < 1024; i += 256) {
        int k = i >> 5, l = i & 31;
        float a = 0.f;
#pragma unroll
        for (int q = 0; q < 32; ++q) a += workS[accOff + k*32 + q] * workS[q*32 + l];
        a *= s_inv;
        workS[accNOff + i] = a;
        workS[3072 + i] += a;
      }
      int tmp = accOff; accOff = accNOff; accNOff = tmp;
      __syncthreads();
    }
    for (int i = t; i < 1024; i += 256)
      psisS[j*1280 + (i>>5)*40 + (i&31)] = f2b(workS[3072+i]);
    __syncthreads();
  }

  // ---- depth loop
  for (int d = 0; d < NDEPTH; ++d) {
    // ===== mix (registers) = sum_j alpha_j * psi_j @ (hcur @ Ws_j)
    f32x4 m00 = {0.f,0.f,0.f,0.f}, m01 = m00, m10 = m00, m11 = m00;
    for (int j = 0; j < NJ; ++j) {
      __syncthreads();
      const ushort_t* Wp = wpk + (size_t)(d*NJ + j)*16384;
      const float alj = alpha[d*NJ + j];
#pragma unroll
      for (int tni = 0; tni < 2; ++tni) {
        int tn = 2*w + tni;
        f32x4 acc0 = {0.f,0.f,0.f,0.f}, acc1 = acc0;
#pragma unroll
        for (int tk = 0; tk < 4; ++tk) {
          bf16x8 b = *(const bf16x8*)(Wp + ((tk*8 + tn) << 9) + (lane << 3));
          int row0 = lane & 15;
          int ba0 = (((row0) << 8) + (tk << 6) + ((lane >> 4) << 4)) ^ ((row0 & 7) << 4);
          bf16x8 a0 = *(const bf16x8*)((const char*)hbS + ba0);
          acc0 = MFMA(a0, b, acc0);
          int row1 = 16 + (lane & 15);
          int ba1 = (((row1) << 8) + (tk << 6) + ((lane >> 4) << 4)) ^ ((row1 & 7) << 4);
          bf16x8 a1 = *(const bf16x8*)((const char*)hbS + ba1);
          acc1 = MFMA(a1, b, acc1);
        }
        int c = tn*16 + (lane & 15);
        int rbase = (lane >> 4) * 4;
#pragma unroll
        for (int r = 0; r < 4; ++r) {
          attnS[c*40 + rbase + r]      = f2b(alj * acc0[r]);
          attnS[c*40 + 16 + rbase + r] = f2b(alj * acc1[r]);
        }
      }
      __syncthreads();
      {
        const char* psj = (const char*)(psisS + j*1280);
        int koff = (lane >> 4) << 4;
        bf16x8 pa0 = *(const bf16x8*)(psj + (lane & 15)*80 + koff);
        bf16x8 pa1 = *(const bf16x8*)(psj + (16 + (lane & 15))*80 + koff);
        int n0 = 2*w*16 + (lane & 15);
        bf16x8 hb0 = *(const bf16x8*)((const char*)attnS + n0*80 + koff);
        bf16x8 hb1 = *(const bf16x8*)((const char*)attnS + (n0 + 16)*80 + koff);
        m00 = MFMA(pa0, hb0, m00);
        m01 = MFMA(pa0, hb1, m01);
        m10 = MFMA(pa1, hb0, m10);
        m11 = MFMA(pa1, hb1, m11);
      }
    }
    __syncthreads();
    // ===== u = hcur + relu(mix + wb) -> workS
    {
      int c0 = 32*w + (lane & 15);
      int c1 = c0 + 16;
      int r0 = (lane >> 4) * 4;
      float wb0 = wb[d*NC + c0], wb1 = wb[d*NC + c1];
#pragma unroll
      for (int r = 0; r < 4; ++r) {
        int row0 = r0 + r, row1 = 16 + r0 + r;
        workS[row0*NC + c0] = hcurS[row0*NC + c0] + fmaxf(m00[r] + wb0, 0.f);
        workS[row0*NC + c1] = hcurS[row0*NC + c1] + fmaxf(m01[r] + wb1, 0.f);
        workS[row1*NC + c0] = hcurS[row1*NC + c0] + fmaxf(m10[r] + wb0, 0.f);
        workS[row1*NC + c1] = hcurS[row1*NC + c1] + fmaxf(m11[r] + wb1, 0.f);
      }
    }
    __syncthreads();
    // ===== LN1: workS -> hcurS + hbS
    {
      const int k = t >> 3, e = t & 7;
      float s = 0.f;
#pragma unroll
      for (int ii = 0; ii < 16; ++ii) s += workS[k*NC + e + 8*ii];
      s += __shfl_xor(s,1); s += __shfl_xor(s,2); s += __shfl_xor(s,4);
      float mu = s * (1.0f/128.0f);
      float vs = 0.f;
#pragma unroll
      for (int ii = 0; ii < 16; ++ii) { float dx = workS[k*NC + e + 8*ii] - mu; vs += dx*dx; }
      vs += __shfl_xor(vs,1); vs += __shfl_xor(vs,2); vs += __shfl_xor(vs,4);
      float rs = rsqrtf(vs*(1.0f/128.0f) + EPSF);
#pragma unroll
      for (int ii = 0; ii < 16; ++ii) {
        int o = e + 8*ii;
        float hv = (workS[k*NC + o] - mu)*rs*ln1g[d*NC + o] + ln1b[d*NC + o];
        hcurS[k*NC + o] = hv;
        int ha = ((k << 8) + (o << 1)) ^ ((k & 7) << 4);
        hbS[ha >> 1] = f2b(hv);
      }
    }
    __syncthreads();
    // ===== attention, per head; o -> workS
    const ushort_t* Wq = wpk + 163840 + (size_t)d*49152;
    for (int h = 0; h < NH; ++h) {
#pragma unroll
      for (int ti = 0; ti < 3; ++ti) {
        int tile = w + ti*4;
        int comp = tile >> 2, mi = (tile >> 1) & 1, ni = tile & 1;
        int tn = comp*8 + h*2 + ni;
        f32x4 acc = {0.f,0.f,0.f,0.f};
#pragma unroll
        for (int tk = 0; tk < 4; ++tk) {
          bf16x8 b = *(const bf16x8*)(Wq + ((tk*24 + tn) << 9) + (lane << 3));
          int row = mi*16 + (lane & 15);
          int ba = ((row << 8) + (tk << 6) + ((lane >> 4) << 4)) ^ ((row & 7) << 4);
          bf16x8 a = *(const bf16x8*)((const char*)hbS + ba);
          acc = MFMA(a, b, acc);
        }
        int ddl = ni*16 + (lane & 15);
        int rb2 = mi*16 + (lane >> 4)*4;
        if (comp == 0) {
#pragma unroll
          for (int r = 0; r < 4; ++r) attnS[(rb2 + r)*40 + ddl] = f2b(acc[r]);
        } else if (comp == 1) {
#pragma unroll
          for (int r = 0; r < 4; ++r) attnS[1280 + (rb2 + r)*40 + ddl] = f2b(acc[r]);
        } else {
#pragma unroll
          for (int r = 0; r < 4; ++r) attnS[2560 + ddl*40 + rb2 + r] = f2b(acc[r]);
        }
      }
      __syncthreads();
      {
        int mi = w >> 1, ni = w & 1;
        int koff = (lane >> 4) << 4;
        bf16x8 qa = *(const bf16x8*)((const char*)attnS + (mi*16 + (lane & 15))*80 + koff);
        bf16x8 kb = *(const bf16x8*)((const char*)(attnS + 1280) + (ni*16 + (lane & 15))*80 + koff);
        f32x4 sc = {0.f,0.f,0.f,0.f};
        sc = MFMA(qa, kb, sc);
        int colL = ni*16 + (lane & 15);
        int rb2 = mi*16 + (lane >> 4)*4;
#pragma unroll
        for (int r = 0; r < 4; ++r) scoresS[(rb2 + r)*33 + colL] = sc[r] * 0.17677669529663687f;
      }
      __syncthreads();
      {
        int row = t >> 3, e = t & 7;
        float v0 = scoresS[row*33 + e],      v1 = scoresS[row*33 + e + 8];
        float v2 = scoresS[row*33 + e + 16], v3 = scoresS[row*33 + e + 24];
        float mx = fmaxf(fmaxf(v0,v1), fmaxf(v2,v3));
        mx = fmaxf(mx, __shfl_xor(mx,1)); mx = fmaxf(mx, __shfl_xor(mx,2)); mx = fmaxf(mx, __shfl_xor(mx,4));
        v0 = expf(v0-mx); v1 = expf(v1-mx); v2 = expf(v2-mx); v3 = expf(v3-mx);
        float s = v0+v1+v2+v3;
        s += __shfl_xor(s,1); s += __shfl_xor(s,2); s += __shfl_xor(s,4);
        float inv = 1.0f/s;
        attnS[3840 + row*40 + e]      = f2b(v0*inv);
        attnS[3840 + row*40 + e + 8]  = f2b(v1*inv);
        attnS[3840 + row*40 + e + 16] = f2b(v2*inv);
        attnS[3840 + row*40 + e + 24] = f2b(v3*inv);
      }
      __syncthreads();
      {
        int mi = w >> 1, ni = w & 1;
        int koff = (lane >> 4) << 4;
        bf16x8 aa = *(const bf16x8*)((const char*)(attnS + 3840) + (mi*16 + (lane & 15))*80 + koff);
        bf16x8 vb = *(const bf16x8*)((const char*)(attnS + 2560) + (ni*16 + (lane & 15))*80 + koff);
        f32x4 ov = {0.f,0.f,0.f,0.f};
        ov = MFMA(aa, vb, ov);
        int col = h*32 + ni*16 + (lane & 15);
        int rb2 = mi*16 + (lane >> 4)*4;
#pragma unroll
        for (int r = 0; r < 4; ++r) workS[(rb2 + r)*NC + col] = ov[r];
      }
      __syncthreads();
    }
    // ===== o -> hbS (bf16, swizzled)
#pragma unroll
    for (int i = 0; i < 16; ++i) {
      int idx = t + 256*i;
      int row = idx >> 7, c = idx & 127;
      int ha = ((row << 8) + (c << 1)) ^ ((row & 7) << 4);
      hbS[ha >> 1] = f2b(workS[idx]);
    }
    __syncthreads();
    // ===== proj: o @ Wo; u2 = hcur + proj -> workS
    const ushort_t* Wop = wpk + 262144 + (size_t)d*16384;
#pragma unroll
    for (int tni = 0; tni < 2; ++tni) {
      int tn = 2*w + tni;
      f32x4 acc0 = {0.f,0.f,0.f,0.f}, acc1 = acc0;
#pragma unroll
      for (int tk = 0; tk < 4; ++tk) {
        bf16x8 b = *(const bf16x8*)(Wop + ((tk*8 + tn) << 9) + (lane << 3));
        int row0 = lane & 15;
        int ba0 = ((row0 << 8) + (tk << 6) + ((lane >> 4) << 4)) ^ ((row0 & 7) << 4);
        bf16x8 a0 = *(const bf16x8*)((const char*)hbS + ba0);
        acc0 = MFMA(a0, b, acc0);
        int row1 = 16 + (lane & 15);
        int ba1 = ((row1 << 8) + (tk << 6) + ((lane >> 4) << 4)) ^ ((row1 & 7) << 4);
        bf16x8 a1 = *(const bf16x8*)((const char*)hbS + ba1);
        acc1 = MFMA(a1, b, acc1);
      }
      int c = tn*16 + (lane & 15);
      int rb2 = (lane >> 4)*4;
#pragma unroll
      for (int r = 0; r < 4; ++r) {
        workS[(rb2 + r)*NC + c]        = hcurS[(rb2 + r)*NC + c]        + acc0[r];
        workS[(16 + rb2 + r)*NC + c]   = hcurS[(16 + rb2 + r)*NC + c]   + acc1[r];
      }
    }
    __syncthreads();
    // ===== LN2: workS -> hcurS + hbS
    {
      const int k = t >> 3, e = t & 7;
      float s = 0.f;
#pragma unroll
      for (int ii = 0; ii < 16; ++ii) s += workS[k*NC + e + 8*ii];
      s += __shfl_xor(s,1); s += __shfl_xor(s,2); s += __shfl_xor(s,4);
      float mu = s * (1.0f/128.0f);
      float vs = 0.f;
#pragma unroll
      for (int ii = 0; ii < 16; ++ii) { float dx = workS[k*NC + e + 8*ii] - mu; vs += dx*dx; }
      vs += __shfl_xor(vs,1); vs += __shfl_xor(vs,2); vs += __shfl_xor(vs,4);
      float rs = rsqrtf(vs*(1.0f/128.0f) + EPSF);
#pragma unroll
      for (int ii = 0; ii < 16; ++ii) {
        int o = e + 8*ii;
        float hv = (workS[k*NC + o] - mu)*rs*ln2g[d*NC + o] + ln2b[d*NC + o];
        hcurS[k*NC + o] = hv;
        int ha = ((k << 8) + (o << 1)) ^ ((k & 7) << 4);
        hbS[ha >> 1] = f2b(hv);
      }
    }
    __syncthreads();
  }
  // ---- maxpool over K
  if (t < NC) {
    float m = hcurS[t];
    for (int k = 1; k < NK; ++k) m = fmaxf(m, hcurS[k*NC + t]);
    out[(size_t)p*NC + t] = m;
  }
}

// ---------------------------------------------------------------- launcher
extern "C" void kernel_launch(void* const* d_in, const int* in_sizes, int n_in,
                              void* d_out, int out_size, void* d_ws, size_t ws_size,
                              hipStream_t stream) {
  const float* xyz    = (const float*)d_in[0];
  const float* points = (const float*)d_in[1];
  const float* w1     = (const float*)d_in[2];
  const float* g1     = (const float*)d_in[3];
  const float* b1     = (const float*)d_in[4];
  const float* w2     = (const float*)d_in[5];
  const float* g2     = (const float*)d_in[6];
  const float* b2     = (const float*)d_in[7];
  const float* w3     = (const float*)d_in[8];
  const float* g3     = (const float*)d_in[9];
  const float* b3     = (const float*)d_in[10];
  const float* wsW    = (const float*)d_in[11];
  const float* wb     = (const float*)d_in[12];
  const float* alpha  = (const float*)d_in[13];
  const float* wqkv   = (const float*)d_in[14];
  const float* wo     = (const float*)d_in[15];
  const float* ln1g   = (const float*)d_in[16];
  const float* ln1b   = (const float*)d_in[17];
  const float* ln2g   = (const float*)d_in[18];
  const float* ln2b   = (const float*)d_in[19];
  float* outp = (float*)d_out;

  float* wsf   = (float*)d_ws;
  float* gnorm = wsf;                        // 786432 f
  float* stats = wsf + 786432;               // 768 f
  float* aff   = wsf + 787200;               // 768 f
  int*   knn   = (int*)(wsf + 787968);       // 262144 i  (reused as wpk after k_layer1)
  ushort_t* wpk = (ushort_t*)(wsf + 787968); // 294912 bf16 (fits in knn's 1 MB)
  float* h2    = wsf + 1050112;              // 16777216 f
  float* hX    = wsf + 17827328;             // 33554432 f

  hipMemsetAsync(stats, 0, 768*sizeof(float), stream);
  k_fps<<<NB, 256, 0, stream>>>(xyz, outp);
  k_knn<<<NPTS, 64, 0, stream>>>(xyz, outp, knn, gnorm);
  k_layer1<<<NM/64, 256, 0, stream>>>(points, knn, gnorm, w1, hX, stats);
  k_pack<<<294912/256, 256, 0, stream>>>(wsW, wqkv, wo, wpk);
  k_finalize<<<1, 128, 0, stream>>>(stats, g1, b1, aff, 64);
  k_layer<64><<<NM/64, 256, 0, stream>>>(hX, aff, w2, h2, stats + 256);
  k_finalize<<<1, 128, 0, stream>>>(stats + 256, g2, b2, aff + 256, 64);
  k_layer<128><<<NM/64, 256, 0, stream>>>(h2, aff + 256, w3, hX, stats + 512);
  k_finalize<<<1, 128, 0, stream>>>(stats + 512, g3, b3, aff + 512, 128);
  k_group<<<NPTS, 256, 0, stream>>>(hX, aff + 512, gnorm, wpk, wb, alpha,
                                    ln1g, ln1b, ln2g, ln2b, outp + (size_t)NB*NS*3);
}

// Round 4
// 2405.436 us; speedup vs baseline: 6.4499x; 1.1673x over previous
//
#include <hip/hip_runtime.h>
#include <math.h>

#define NB 8
#define NP 4096
#define NCIN 64
#define NS 1024
#define NK 32
#define NC 128
#define NJ 5
#define NDEPTH 2
#define NH 4
#define NPTS (NB*NS)       /* 8192 groups */
#define NM (NPTS*NK)       /* 262144 rows */
#define EPSF 1e-5f

typedef float f32x4 __attribute__((ext_vector_type(4)));
typedef short bf16x8 __attribute__((ext_vector_type(8)));
typedef unsigned short ushort_t;
typedef unsigned long long u64;

#define MFMA(a,b,c) __builtin_amdgcn_mfma_f32_16x16x32_bf16(a,b,c,0,0,0)

__device__ __forceinline__ ushort_t f2b(float f) {
  unsigned int u = __float_as_uint(f);
  u = (u + 0x7fffu + ((u >> 16) & 1u)) >> 16;
  return (ushort_t)u;
}

// ---------------------------------------------------------------- FPS
// 256 threads, 16 pts/lane in registers. u64-packed (distbits<<32 | ~idx)
// argmax: exact value order (dist>=0), lowest-index tie-break.
// NO global stores inside the step loop (centroids -> LDS, stored at end),
// so the per-step barrier waits only on lgkmcnt, not vmcnt.
__global__ __launch_bounds__(256) void k_fps(const float* __restrict__ xyz,
                                             float* __restrict__ newxyz) {
  const int b = blockIdx.x;
  const int t = threadIdx.x;
  const int lane = t & 63;
  const int w = t >> 6;
  __shared__ float Xl[NP*3];            // 48 KB coord stage
  __shared__ float cenL[NS*3];          // 12 KB centroid list
  __shared__ u64 slot[2][4];            // parity double-buffered wave results
  const float* X = xyz + (size_t)b * NP * 3;
  for (int i = t; i < NP*3; i += 256) Xl[i] = X[i];
  __syncthreads();
  float px[16], py[16], pz[16], dist[16];
#pragma unroll
  for (int i = 0; i < 16; ++i) {
    int n = t + 256*i;
    px[i] = Xl[3*n]; py[i] = Xl[3*n+1]; pz[i] = Xl[3*n+2];
    dist[i] = 1e10f;
  }
  int far = 0;
  for (int s = 0; s < NS; ++s) {
    // centroid: same-address LDS broadcast (far uniform across block)
    float cx = Xl[3*far], cy = Xl[3*far+1], cz = Xl[3*far+2];
    if (t == 0) { cenL[3*s] = cx; cenL[3*s+1] = cy; cenL[3*s+2] = cz; }
    u64 pk[16];
#pragma unroll
    for (int i = 0; i < 16; ++i) {
      float dx = px[i]-cx, dy = py[i]-cy, dz = pz[i]-cz;
      float d = fmaf(dx,dx, fmaf(dy,dy, dz*dz));
      float nd = fminf(dist[i], d);
      dist[i] = nd;
      pk[i] = ((u64)__float_as_uint(nd) << 32) | (unsigned)(~(t + 256*i));
    }
    // depth-4 tree max (independent compares, short dep chain)
#pragma unroll
    for (int st = 1; st < 16; st <<= 1)
#pragma unroll
      for (int i = 0; i < 16; i += 2*st)
        pk[i] = pk[i+st] > pk[i] ? pk[i+st] : pk[i];
    u64 best = pk[0];
#pragma unroll
    for (int off = 32; off; off >>= 1) {
      u64 o = __shfl_xor(best, off);
      best = o > best ? o : best;
    }
    if (lane == 0) slot[s&1][w] = best;
    __syncthreads();
    u64 s0 = slot[s&1][0], s1 = slot[s&1][1], s2 = slot[s&1][2], s3 = slot[s&1][3];
    s0 = s1 > s0 ? s1 : s0;
    s2 = s3 > s2 ? s3 : s2;
    s0 = s2 > s0 ? s2 : s0;
    far = (int)(~(unsigned)s0);          // low 32 bits hold ~n
  }
  __syncthreads();
  float* o = newxyz + (size_t)b * NS * 3;
  for (int i = t; i < NS*3; i += 256) o[i] = cenL[i];
}

// ---------------------------------------------------------------- KNN: one wave per query, zero barriers
__global__ __launch_bounds__(64) void k_knn(const float* __restrict__ xyz,
                                            const float* __restrict__ newxyz,
                                            int* __restrict__ knn_idx,
                                            float* __restrict__ gnorm) {
  const int p = blockIdx.x;
  const int b = p >> 10;
  const int lane = threadIdx.x;
  const float* X = xyz + (size_t)b * NP * 3;
  __shared__ float d2[NP];            // 16 KB -> 10 waves/CU
  float cx = newxyz[3*p], cy = newxyz[3*p+1], cz = newxyz[3*p+2];
  float sc = cx*cx + cy*cy + cz*cz;
#pragma unroll 4
  for (int i = 0; i < NP/64; ++i) {
    int n = lane + 64*i;              // bank-conflict-free (2 lanes/bank)
    float x = X[3*n], y = X[3*n+1], z = X[3*n+2];
    float sx = x*x + y*y + z*z;
    float dot = cx*x + cy*y + cz*z;
    d2[n] = sc + sx - 2.0f*dot;       // same formula/rounding as reference
  }
  for (int it = 0; it < NK; ++it) {
    float bv = 3.0e38f; int bi = 0x7fffffff;
#pragma unroll 8
    for (int i = 0; i < NP/64; ++i) {
      int n = lane + 64*i;            // ascending n per lane
      float v = d2[n];
      if (v < bv) { bv = v; bi = n; }
    }
#pragma unroll
    for (int off = 32; off; off >>= 1) {
      float ov = __shfl_xor(bv, off);
      int   oi = __shfl_xor(bi, off);
      if (ov < bv || (ov == bv && oi < bi)) { bv = ov; bi = oi; }
    }
    if (lane == 0) {
      d2[bi] = 3.3e38f;               // wave-synchronous; visible next iter
      knn_idx[p*NK + it] = bi;
      float* g = gnorm + ((size_t)p*NK + it)*3;
      g[0] = X[3*bi]   - cx;
      g[1] = X[3*bi+1] - cy;
      g[2] = X[3*bi+2] - cz;
    }
  }
}

// ---------------------------------------------------------------- MLP layer 1
__global__ __launch_bounds__(256) void k_layer1(const float* __restrict__ points,
                                                const int* __restrict__ knn_idx,
                                                const float* __restrict__ gnorm,
                                                const float* __restrict__ w1,
                                                float* __restrict__ y,
                                                float* __restrict__ stats) {
  const int r0 = blockIdx.x * 64;
  const int t = threadIdx.x;
  __shared__ float Xs[64][69];
  __shared__ float Ws[64][69];
  __shared__ int nid[64];
  __shared__ float ps[4][64], pss[4][64];
  if (t < 64) nid[t] = knn_idx[r0 + t];
  __syncthreads();
  for (int idx = t; idx < 64*67; idx += 256) {
    int r = idx / 67, c = idx % 67;
    int row = r0 + r;
    float v;
    if (c < 3) v = gnorm[(size_t)row*3 + c];
    else {
      int bb = row >> 15;
      int n = nid[r];
      v = points[((size_t)bb*NP + n)*NCIN + (c-3)];
    }
    Xs[r][c] = v;
  }
  for (int idx = t; idx < 64*67; idx += 256) {
    int o = idx / 67, c = idx % 67;
    Ws[o][c] = w1[idx];
  }
  __syncthreads();
  const int col = t & 63;
  const int rb  = t >> 6;
  float s1 = 0.f, s2 = 0.f;
  for (int i = 0; i < 16; ++i) {
    int r = rb + 4*i;
    float acc = 0.f;
#pragma unroll
    for (int c = 0; c < 67; ++c) acc += Xs[r][c] * Ws[col][c];
    y[(size_t)(r0 + r)*64 + col] = acc;
    s1 += acc; s2 += acc*acc;
  }
  ps[rb][col] = s1; pss[rb][col] = s2;
  __syncthreads();
  if (t < 64) {
    float a = ps[0][t]+ps[1][t]+ps[2][t]+ps[3][t];
    float q = pss[0][t]+pss[1][t]+pss[2][t]+pss[3][t];
    atomicAdd(&stats[t], a);
    atomicAdd(&stats[64 + t], q);
  }
}

// ---------------------------------------------------------------- MLP layers 2/3
template <int COUT>
__global__ __launch_bounds__(256) void k_layer(const float* __restrict__ xin,
                                               const float* __restrict__ aff,
                                               const float* __restrict__ w,
                                               float* __restrict__ y,
                                               float* __restrict__ stats) {
  const int r0 = blockIdx.x * 64;
  const int t = threadIdx.x;
  __shared__ float Xs[64][65];
  __shared__ float Ws[COUT][65];
  __shared__ float sa[64], sb[64];
  constexpr int NTR = 256 / COUT;
  __shared__ float ps[NTR][COUT], pss[NTR][COUT];
  if (t < 64) { sa[t] = aff[t]; sb[t] = aff[64 + t]; }
  __syncthreads();
  for (int idx = t; idx < 64*64; idx += 256) {
    int r = idx >> 6, c = idx & 63;
    float v = xin[(size_t)r0*64 + idx];
    Xs[r][c] = fmaxf(sa[c]*v + sb[c], 0.0f);
  }
  for (int idx = t; idx < COUT*64; idx += 256) {
    int o = idx >> 6, c = idx & 63;
    Ws[o][c] = w[idx];
  }
  __syncthreads();
  const int col = t & (COUT-1);
  const int rb  = t / COUT;
  float s1 = 0.f, s2 = 0.f;
  for (int i = 0; i < 64/NTR; ++i) {
    int r = rb + NTR*i;
    float acc = 0.f;
#pragma unroll
    for (int c = 0; c < 64; ++c) acc += Xs[r][c] * Ws[col][c];
    y[(size_t)(r0 + r)*COUT + col] = acc;
    s1 += acc; s2 += acc*acc;
  }
  ps[rb][col] = s1; pss[rb][col] = s2;
  __syncthreads();
  if (t < COUT) {
    float a = 0.f, q = 0.f;
    for (int n = 0; n < NTR; ++n) { a += ps[n][t]; q += pss[n][t]; }
    atomicAdd(&stats[t], a);
    atomicAdd(&stats[COUT + t], q);
  }
}

// ---------------------------------------------------------------- BN stats -> affine
__global__ void k_finalize(const float* __restrict__ stats, const float* __restrict__ g,
                           const float* __restrict__ b, float* __restrict__ aff, int cout) {
  int t = threadIdx.x;
  if (t < cout) {
    const float inv = 1.0f / (float)NM;
    float m = stats[t] * inv;
    float var = stats[cout + t] * inv - m*m;
    float a = g[t] * rsqrtf(var + EPSF);
    aff[t] = a;
    aff[cout + t] = b[t] - m * a;
  }
}

// ---------------------------------------------------------------- pack weights to bf16 MFMA B-fragment layout
__global__ __launch_bounds__(256) void k_pack(const float* __restrict__ ws,
                                              const float* __restrict__ wqkv,
                                              const float* __restrict__ wo,
                                              ushort_t* __restrict__ wpk) {
  int gid = blockIdx.x*256 + threadIdx.x;    // < 294912
  const float* src; int N_; int rem;
  if (gid < 163840)      { int mat = gid >> 14; rem = gid & 16383; src = ws  + (size_t)mat*16384; N_ = 128; }
  else if (gid < 262144) { int g2 = gid - 163840; int d = g2/49152; rem = g2 - d*49152; src = wqkv + (size_t)d*49152; N_ = 384; }
  else                   { int g3 = gid - 262144; int d = g3 >> 14; rem = g3 & 16383;  src = wo  + (size_t)d*16384; N_ = 128; }
  int NTN = N_ >> 4;
  int tile = rem >> 9, r = rem & 511;
  int tk = tile / NTN, tn = tile % NTN;
  int lane2 = r >> 3, jj = r & 7;
  int k = tk*32 + (lane2 >> 4)*8 + jj;
  int n = tn*16 + (lane2 & 15);
  wpk[gid] = f2b(src[(size_t)k*N_ + n]);
}

// ---------------------------------------------------------------- fused per-group (MFMA version)
__global__ __launch_bounds__(256) void k_group(
    const float* __restrict__ h3, const float* __restrict__ aff3,
    const float* __restrict__ gnorm,
    const ushort_t* __restrict__ wpk,
    const float* __restrict__ wb, const float* __restrict__ alpha,
    const float* __restrict__ ln1g, const float* __restrict__ ln1b,
    const float* __restrict__ ln2g, const float* __restrict__ ln2b,
    float* __restrict__ out) {
  const int p = blockIdx.x;
  const int t = threadIdx.x;
  const int lane = t & 63;
  const int w = t >> 6;

  __shared__ __align__(16) float   hcurS[NK*NC];     // 16 KB fp32 activations
  __shared__ __align__(16) ushort_t hbS[NK*NC];      // 8 KB bf16 mirror, XOR-swizzled rows
  __shared__ __align__(16) float   workS[NK*NC];     // 16 KB scratch
  __shared__ __align__(16) ushort_t attnS[5120];     // 10 KB
  __shared__ __align__(16) float   scoresS[1056];    // scores [32][33]; init: px, dinv
  __shared__ __align__(16) ushort_t psisS[5*32*40];  // 12.5 KB

  // ---- init: px, pf -> hcur/hb
  if (t < 96) scoresS[t] = gnorm[(size_t)p*96 + t];
  const float* h3p = h3 + (size_t)p*4096;
#pragma unroll
  for (int i = 0; i < 16; ++i) {
    int idx = t + 256*i;
    int c = idx & 127, row = idx >> 7;
    float v = fmaxf(aff3[c]*h3p[idx] + aff3[128+c], 0.f);
    hcurS[idx] = v;
    int ha = ((row << 8) + (c << 1)) ^ ((row & 7) << 4);
    hbS[ha >> 1] = f2b(v);
  }
  __syncthreads();
  // ---- dd -> workS[1024:2048)
  for (int i = t; i < 1024; i += 256) {
    int k = i >> 5, l = i & 31;
    float dx = scoresS[k*3]  -scoresS[l*3];
    float dy = scoresS[k*3+1]-scoresS[l*3+1];
    float dz = scoresS[k*3+2]-scoresS[l*3+2];
    workS[1024+i] = dx*dx + dy*dy + dz*dz;
  }
  __syncthreads();
  // ---- sigma
  float part = 0.f;
  for (int i = t; i < 1024; i += 256) part += sqrtf(workS[1024+i] + 1e-12f);
#pragma unroll
  for (int off = 32; off; off >>= 1) part += __shfl_xor(part, off);
  if (lane == 0) workS[2048 + w] = part;
  __syncthreads();
  if (t == 0) {
    float sg = (workS[2048]+workS[2049]+workS[2050]+workS[2051]) * (1.0f/1024.0f);
    workS[2052] = 2.0f*sg*sg + 1e-12f;
  }
  __syncthreads();
  const float denom = workS[2052];
  for (int i = t; i < 1024; i += 256) workS[1024+i] = expf(-workS[1024+i] / denom);  // A
  __syncthreads();
  if (t < 32) {
    float s = 0.f;
    for (int l = 0; l < 32; ++l) s += workS[1024 + t*32 + l];
    scoresS[96 + t] = rsqrtf(s + 1e-12f);    // dinv
  }
  __syncthreads();
  for (int i = t; i < 1024; i += 256) {      // L -> workS[0:1024)
    int k = i >> 5, l = i & 31;
    float v = -(scoresS[96+k] * workS[1024+i] * scoresS[96+l]);
    if (k == l) v += 1.0f;
    workS[i] = v;
  }
  __syncthreads();

  // ---- psis (once): T_j = I + sum_{m=1..4} M^m/m!, M = sj*L
  for (int j = 0; j < NJ; ++j) {
    const float sj = -0.05f * (float)(1 << j);
    for (int i = t; i < 1024; i += 256) {
      float m = sj * workS[i];
      workS[1024+i] = m;
      workS[3072+i] = (((i>>5) == (i&31)) ? 1.0f : 0.0f) + m;
    }
    __syncthreads();
    int accOff = 1024, accNOff = 2048;
    for (int m = 2; m <= 4; ++m) {
      const float s_inv = sj / (float)m;
      for (int i = t; i < 1024; i += 256) {
        int k = i >> 5, l = i & 31;
        float a = 0.f;
#pragma unroll
        for (int q = 0; q < 32; ++q) a += workS[accOff + k*32 + q] * workS[q*32 + l];
        a *= s_inv;
        workS[accNOff + i] = a;
        workS[3072 + i] += a;
      }
      int tmp = accOff; accOff = accNOff; accNOff = tmp;
      __syncthreads();
    }
    for (int i = t; i < 1024; i += 256)
      psisS[j*1280 + (i>>5)*40 + (i&31)] = f2b(workS[3072+i]);
    __syncthreads();
  }

  // ---- depth loop
  for (int d = 0; d < NDEPTH; ++d) {
    // ===== mix (registers) = sum_j alpha_j * psi_j @ (hcur @ Ws_j)
    f32x4 m00 = {0.f,0.f,0.f,0.f}, m01 = m00, m10 = m00, m11 = m00;
    for (int j = 0; j < NJ; ++j) {
      __syncthreads();
      const ushort_t* Wp = wpk + (size_t)(d*NJ + j)*16384;
      const float alj = alpha[d*NJ + j];
#pragma unroll
      for (int tni = 0; tni < 2; ++tni) {
        int tn = 2*w + tni;
        f32x4 acc0 = {0.f,0.f,0.f,0.f}, acc1 = acc0;
#pragma unroll
        for (int tk = 0; tk < 4; ++tk) {
          bf16x8 b = *(const bf16x8*)(Wp + ((tk*8 + tn) << 9) + (lane << 3));
          int row0 = lane & 15;
          int ba0 = (((row0) << 8) + (tk << 6) + ((lane >> 4) << 4)) ^ ((row0 & 7) << 4);
          bf16x8 a0 = *(const bf16x8*)((const char*)hbS + ba0);
          acc0 = MFMA(a0, b, acc0);
          int row1 = 16 + (lane & 15);
          int ba1 = (((row1) << 8) + (tk << 6) + ((lane >> 4) << 4)) ^ ((row1 & 7) << 4);
          bf16x8 a1 = *(const bf16x8*)((const char*)hbS + ba1);
          acc1 = MFMA(a1, b, acc1);
        }
        int c = tn*16 + (lane & 15);
        int rbase = (lane >> 4) * 4;
#pragma unroll
        for (int r = 0; r < 4; ++r) {
          attnS[c*40 + rbase + r]      = f2b(alj * acc0[r]);
          attnS[c*40 + 16 + rbase + r] = f2b(alj * acc1[r]);
        }
      }
      __syncthreads();
      {
        const char* psj = (const char*)(psisS + j*1280);
        int koff = (lane >> 4) << 4;
        bf16x8 pa0 = *(const bf16x8*)(psj + (lane & 15)*80 + koff);
        bf16x8 pa1 = *(const bf16x8*)(psj + (16 + (lane & 15))*80 + koff);
        int n0 = 2*w*16 + (lane & 15);
        bf16x8 hb0 = *(const bf16x8*)((const char*)attnS + n0*80 + koff);
        bf16x8 hb1 = *(const bf16x8*)((const char*)attnS + (n0 + 16)*80 + koff);
        m00 = MFMA(pa0, hb0, m00);
        m01 = MFMA(pa0, hb1, m01);
        m10 = MFMA(pa1, hb0, m10);
        m11 = MFMA(pa1, hb1, m11);
      }
    }
    __syncthreads();
    // ===== u = hcur + relu(mix + wb) -> workS
    {
      int c0 = 32*w + (lane & 15);
      int c1 = c0 + 16;
      int r0 = (lane >> 4) * 4;
      float wb0 = wb[d*NC + c0], wb1 = wb[d*NC + c1];
#pragma unroll
      for (int r = 0; r < 4; ++r) {
        int row0 = r0 + r, row1 = 16 + r0 + r;
        workS[row0*NC + c0] = hcurS[row0*NC + c0] + fmaxf(m00[r] + wb0, 0.f);
        workS[row0*NC + c1] = hcurS[row0*NC + c1] + fmaxf(m01[r] + wb1, 0.f);
        workS[row1*NC + c0] = hcurS[row1*NC + c0] + fmaxf(m10[r] + wb0, 0.f);
        workS[row1*NC + c1] = hcurS[row1*NC + c1] + fmaxf(m11[r] + wb1, 0.f);
      }
    }
    __syncthreads();
    // ===== LN1: workS -> hcurS + hbS
    {
      const int k = t >> 3, e = t & 7;
      float s = 0.f;
#pragma unroll
      for (int ii = 0; ii < 16; ++ii) s += workS[k*NC + e + 8*ii];
      s += __shfl_xor(s,1); s += __shfl_xor(s,2); s += __shfl_xor(s,4);
      float mu = s * (1.0f/128.0f);
      float vs = 0.f;
#pragma unroll
      for (int ii = 0; ii < 16; ++ii) { float dx = workS[k*NC + e + 8*ii] - mu; vs += dx*dx; }
      vs += __shfl_xor(vs,1); vs += __shfl_xor(vs,2); vs += __shfl_xor(vs,4);
      float rs = rsqrtf(vs*(1.0f/128.0f) + EPSF);
#pragma unroll
      for (int ii = 0; ii < 16; ++ii) {
        int o = e + 8*ii;
        float hv = (workS[k*NC + o] - mu)*rs*ln1g[d*NC + o] + ln1b[d*NC + o];
        hcurS[k*NC + o] = hv;
        int ha = ((k << 8) + (o << 1)) ^ ((k & 7) << 4);
        hbS[ha >> 1] = f2b(hv);
      }
    }
    __syncthreads();
    // ===== attention, per head; o -> workS
    const ushort_t* Wq = wpk + 163840 + (size_t)d*49152;
    for (int h = 0; h < NH; ++h) {
#pragma unroll
      for (int ti = 0; ti < 3; ++ti) {
        int tile = w + ti*4;
        int comp = tile >> 2, mi = (tile >> 1) & 1, ni = tile & 1;
        int tn = comp*8 + h*2 + ni;
        f32x4 acc = {0.f,0.f,0.f,0.f};
#pragma unroll
        for (int tk = 0; tk < 4; ++tk) {
          bf16x8 b = *(const bf16x8*)(Wq + ((tk*24 + tn) << 9) + (lane << 3));
          int row = mi*16 + (lane & 15);
          int ba = ((row << 8) + (tk << 6) + ((lane >> 4) << 4)) ^ ((row & 7) << 4);
          bf16x8 a = *(const bf16x8*)((const char*)hbS + ba);
          acc = MFMA(a, b, acc);
        }
        int ddl = ni*16 + (lane & 15);
        int rb2 = mi*16 + (lane >> 4)*4;
        if (comp == 0) {
#pragma unroll
          for (int r = 0; r < 4; ++r) attnS[(rb2 + r)*40 + ddl] = f2b(acc[r]);
        } else if (comp == 1) {
#pragma unroll
          for (int r = 0; r < 4; ++r) attnS[1280 + (rb2 + r)*40 + ddl] = f2b(acc[r]);
        } else {
#pragma unroll
          for (int r = 0; r < 4; ++r) attnS[2560 + ddl*40 + rb2 + r] = f2b(acc[r]);
        }
      }
      __syncthreads();
      {
        int mi = w >> 1, ni = w & 1;
        int koff = (lane >> 4) << 4;
        bf16x8 qa = *(const bf16x8*)((const char*)attnS + (mi*16 + (lane & 15))*80 + koff);
        bf16x8 kb = *(const bf16x8*)((const char*)(attnS + 1280) + (ni*16 + (lane & 15))*80 + koff);
        f32x4 sc = {0.f,0.f,0.f,0.f};
        sc = MFMA(qa, kb, sc);
        int colL = ni*16 + (lane & 15);
        int rb2 = mi*16 + (lane >> 4)*4;
#pragma unroll
        for (int r = 0; r < 4; ++r) scoresS[(rb2 + r)*33 + colL] = sc[r] * 0.17677669529663687f;
      }
      __syncthreads();
      {
        int row = t >> 3, e = t & 7;
        float v0 = scoresS[row*33 + e],      v1 = scoresS[row*33 + e + 8];
        float v2 = scoresS[row*33 + e + 16], v3 = scoresS[row*33 + e + 24];
        float mx = fmaxf(fmaxf(v0,v1), fmaxf(v2,v3));
        mx = fmaxf(mx, __shfl_xor(mx,1)); mx = fmaxf(mx, __shfl_xor(mx,2)); mx = fmaxf(mx, __shfl_xor(mx,4));
        v0 = expf(v0-mx); v1 = expf(v1-mx); v2 = expf(v2-mx); v3 = expf(v3-mx);
        float s = v0+v1+v2+v3;
        s += __shfl_xor(s,1); s += __shfl_xor(s,2); s += __shfl_xor(s,4);
        float inv = 1.0f/s;
        attnS[3840 + row*40 + e]      = f2b(v0*inv);
        attnS[3840 + row*40 + e + 8]  = f2b(v1*inv);
        attnS[3840 + row*40 + e + 16] = f2b(v2*inv);
        attnS[3840 + row*40 + e + 24] = f2b(v3*inv);
      }
      __syncthreads();
      {
        int mi = w >> 1, ni = w & 1;
        int koff = (lane >> 4) << 4;
        bf16x8 aa = *(const bf16x8*)((const char*)(attnS + 3840) + (mi*16 + (lane & 15))*80 + koff);
        bf16x8 vb = *(const bf16x8*)((const char*)(attnS + 2560) + (ni*16 + (lane & 15))*80 + koff);
        f32x4 ov = {0.f,0.f,0.f,0.f};
        ov = MFMA(aa, vb, ov);
        int col = h*32 + ni*16 + (lane & 15);
        int rb2 = mi*16 + (lane >> 4)*4;
#pragma unroll
        for (int r = 0; r < 4; ++r) workS[(rb2 + r)*NC + col] = ov[r];
      }
      __syncthreads();
    }
    // ===== o -> hbS (bf16, swizzled)
#pragma unroll
    for (int i = 0; i < 16; ++i) {
      int idx = t + 256*i;
      int row = idx >> 7, c = idx & 127;
      int ha = ((row << 8) + (c << 1)) ^ ((row & 7) << 4);
      hbS[ha >> 1] = f2b(workS[idx]);
    }
    __syncthreads();
    // ===== proj: o @ Wo; u2 = hcur + proj -> workS
    const ushort_t* Wop = wpk + 262144 + (size_t)d*16384;
#pragma unroll
    for (int tni = 0; tni < 2; ++tni) {
      int tn = 2*w + tni;
      f32x4 acc0 = {0.f,0.f,0.f,0.f}, acc1 = acc0;
#pragma unroll
      for (int tk = 0; tk < 4; ++tk) {
        bf16x8 b = *(const bf16x8*)(Wop + ((tk*8 + tn) << 9) + (lane << 3));
        int row0 = lane & 15;
        int ba0 = ((row0 << 8) + (tk << 6) + ((lane >> 4) << 4)) ^ ((row0 & 7) << 4);
        bf16x8 a0 = *(const bf16x8*)((const char*)hbS + ba0);
        acc0 = MFMA(a0, b, acc0);
        int row1 = 16 + (lane & 15);
        int ba1 = ((row1 << 8) + (tk << 6) + ((lane >> 4) << 4)) ^ ((row1 & 7) << 4);
        bf16x8 a1 = *(const bf16x8*)((const char*)hbS + ba1);
        acc1 = MFMA(a1, b, acc1);
      }
      int c = tn*16 + (lane & 15);
      int rb2 = (lane >> 4)*4;
#pragma unroll
      for (int r = 0; r < 4; ++r) {
        workS[(rb2 + r)*NC + c]        = hcurS[(rb2 + r)*NC + c]        + acc0[r];
        workS[(16 + rb2 + r)*NC + c]   = hcurS[(16 + rb2 + r)*NC + c]   + acc1[r];
      }
    }
    __syncthreads();
    // ===== LN2: workS -> hcurS + hbS
    {
      const int k = t >> 3, e = t & 7;
      float s = 0.f;
#pragma unroll
      for (int ii = 0; ii < 16; ++ii) s += workS[k*NC + e + 8*ii];
      s += __shfl_xor(s,1); s += __shfl_xor(s,2); s += __shfl_xor(s,4);
      float mu = s * (1.0f/128.0f);
      float vs = 0.f;
#pragma unroll
      for (int ii = 0; ii < 16; ++ii) { float dx = workS[k*NC + e + 8*ii] - mu; vs += dx*dx; }
      vs += __shfl_xor(vs,1); vs += __shfl_xor(vs,2); vs += __shfl_xor(vs,4);
      float rs = rsqrtf(vs*(1.0f/128.0f) + EPSF);
#pragma unroll
      for (int ii = 0; ii < 16; ++ii) {
        int o = e + 8*ii;
        float hv = (workS[k*NC + o] - mu)*rs*ln2g[d*NC + o] + ln2b[d*NC + o];
        hcurS[k*NC + o] = hv;
        int ha = ((k << 8) + (o << 1)) ^ ((k & 7) << 4);
        hbS[ha >> 1] = f2b(hv);
      }
    }
    __syncthreads();
  }
  // ---- maxpool over K
  if (t < NC) {
    float m = hcurS[t];
    for (int k = 1; k < NK; ++k) m = fmaxf(m, hcurS[k*NC + t]);
    out[(size_t)p*NC + t] = m;
  }
}

// ---------------------------------------------------------------- launcher
extern "C" void kernel_launch(void* const* d_in, const int* in_sizes, int n_in,
                              void* d_out, int out_size, void* d_ws, size_t ws_size,
                              hipStream_t stream) {
  const float* xyz    = (const float*)d_in[0];
  const float* points = (const float*)d_in[1];
  const float* w1     = (const float*)d_in[2];
  const float* g1     = (const float*)d_in[3];
  const float* b1     = (const float*)d_in[4];
  const float* w2     = (const float*)d_in[5];
  const float* g2     = (const float*)d_in[6];
  const float* b2     = (const float*)d_in[7];
  const float* w3     = (const float*)d_in[8];
  const float* g3     = (const float*)d_in[9];
  const float* b3     = (const float*)d_in[10];
  const float* wsW    = (const float*)d_in[11];
  const float* wb     = (const float*)d_in[12];
  const float* alpha  = (const float*)d_in[13];
  const float* wqkv   = (const float*)d_in[14];
  const float* wo     = (const float*)d_in[15];
  const float* ln1g   = (const float*)d_in[16];
  const float* ln1b   = (const float*)d_in[17];
  const float* ln2g   = (const float*)d_in[18];
  const float* ln2b   = (const float*)d_in[19];
  float* outp = (float*)d_out;

  float* wsf   = (float*)d_ws;
  float* gnorm = wsf;                        // 786432 f
  float* stats = wsf + 786432;               // 768 f
  float* aff   = wsf + 787200;               // 768 f
  int*   knn   = (int*)(wsf + 787968);       // 262144 i  (reused as wpk after k_layer1)
  ushort_t* wpk = (ushort_t*)(wsf + 787968); // 294912 bf16 (fits in knn's 1 MB)
  float* h2    = wsf + 1050112;              // 16777216 f
  float* hX    = wsf + 17827328;             // 33554432 f

  hipMemsetAsync(stats, 0, 768*sizeof(float), stream);
  k_fps<<<NB, 256, 0, stream>>>(xyz, outp);
  k_knn<<<NPTS, 64, 0, stream>>>(xyz, outp, knn, gnorm);
  k_layer1<<<NM/64, 256, 0, stream>>>(points, knn, gnorm, w1, hX, stats);
  k_pack<<<294912/256, 256, 0, stream>>>(wsW, wqkv, wo, wpk);
  k_finalize<<<1, 128, 0, stream>>>(stats, g1, b1, aff, 64);
  k_layer<64><<<NM/64, 256, 0, stream>>>(hX, aff, w2, h2, stats + 256);
  k_finalize<<<1, 128, 0, stream>>>(stats + 256, g2, b2, aff + 256, 64);
  k_layer<128><<<NM/64, 256, 0, stream>>>(h2, aff + 256, w3, hX, stats + 512);
  k_finalize<<<1, 128, 0, stream>>>(stats + 512, g3, b3, aff + 512, 128);
  k_group<<<NPTS, 256, 0, stream>>>(hX, aff + 512, gnorm, wpk, wb, alpha,
                                    ln1g, ln1b, ln2g, ln2b, outp + (size_t)NB*NS*3);
}

// Round 5
// 2018.925 us; speedup vs baseline: 7.6847x; 1.1914x over previous
//
#include <hip/hip_runtime.h>
#include <math.h>

#define NB 8
#define NP 4096
#define NCIN 64
#define NS 1024
#define NK 32
#define NC 128
#define NJ 5
#define NDEPTH 2
#define NH 4
#define NPTS (NB*NS)       /* 8192 groups */
#define NM (NPTS*NK)       /* 262144 rows */
#define EPSF 1e-5f

typedef float f32x4 __attribute__((ext_vector_type(4)));
typedef short bf16x8 __attribute__((ext_vector_type(8)));
typedef unsigned short ushort_t;
typedef unsigned long long u64;

#define MFMA(a,b,c) __builtin_amdgcn_mfma_f32_16x16x32_bf16(a,b,c,0,0,0)

__device__ __forceinline__ ushort_t f2b(float f) {
  unsigned int u = __float_as_uint(f);
  u = (u + 0x7fffu + ((u >> 16) & 1u)) >> 16;
  return (ushort_t)u;
}
__device__ __forceinline__ float b2f(ushort_t h) {
  unsigned int u = ((unsigned int)h) << 16;
  return __uint_as_float(u);
}

// ---------------------------------------------------------------- FPS
__global__ __launch_bounds__(256) void k_fps(const float* __restrict__ xyz,
                                             float* __restrict__ newxyz) {
  const int b = blockIdx.x;
  const int t = threadIdx.x;
  const int lane = t & 63;
  const int w = t >> 6;
  __shared__ float Xl[NP*3];
  __shared__ float cenL[NS*3];
  __shared__ u64 slot[2][4];
  const float* X = xyz + (size_t)b * NP * 3;
  for (int i = t; i < NP*3; i += 256) Xl[i] = X[i];
  __syncthreads();
  float px[16], py[16], pz[16], dist[16];
#pragma unroll
  for (int i = 0; i < 16; ++i) {
    int n = t + 256*i;
    px[i] = Xl[3*n]; py[i] = Xl[3*n+1]; pz[i] = Xl[3*n+2];
    dist[i] = 1e10f;
  }
  int far = 0;
  for (int s = 0; s < NS; ++s) {
    float cx = Xl[3*far], cy = Xl[3*far+1], cz = Xl[3*far+2];
    if (t == 0) { cenL[3*s] = cx; cenL[3*s+1] = cy; cenL[3*s+2] = cz; }
    u64 pk[16];
#pragma unroll
    for (int i = 0; i < 16; ++i) {
      float dx = px[i]-cx, dy = py[i]-cy, dz = pz[i]-cz;
      float d = fmaf(dx,dx, fmaf(dy,dy, dz*dz));
      float nd = fminf(dist[i], d);
      dist[i] = nd;
      pk[i] = ((u64)__float_as_uint(nd) << 32) | (unsigned)(~(t + 256*i));
    }
#pragma unroll
    for (int st = 1; st < 16; st <<= 1)
#pragma unroll
      for (int i = 0; i < 16; i += 2*st)
        pk[i] = pk[i+st] > pk[i] ? pk[i+st] : pk[i];
    u64 best = pk[0];
#pragma unroll
    for (int off = 32; off; off >>= 1) {
      u64 o = __shfl_xor(best, off);
      best = o > best ? o : best;
    }
    if (lane == 0) slot[s&1][w] = best;
    __syncthreads();
    u64 s0 = slot[s&1][0], s1 = slot[s&1][1], s2 = slot[s&1][2], s3 = slot[s&1][3];
    s0 = s1 > s0 ? s1 : s0;
    s2 = s3 > s2 ? s3 : s2;
    s0 = s2 > s0 ? s2 : s0;
    far = (int)(~(unsigned)s0);
  }
  __syncthreads();
  float* o = newxyz + (size_t)b * NS * 3;
  for (int i = t; i < NS*3; i += 256) o[i] = cenL[i];
}

// ---------------------------------------------------------------- KNN
__global__ __launch_bounds__(64) void k_knn(const float* __restrict__ xyz,
                                            const float* __restrict__ newxyz,
                                            int* __restrict__ knn_idx,
                                            float* __restrict__ gnorm) {
  const int p = blockIdx.x;
  const int b = p >> 10;
  const int lane = threadIdx.x;
  const float* X = xyz + (size_t)b * NP * 3;
  __shared__ float d2[NP];
  float cx = newxyz[3*p], cy = newxyz[3*p+1], cz = newxyz[3*p+2];
  float sc = cx*cx + cy*cy + cz*cz;
#pragma unroll 4
  for (int i = 0; i < NP/64; ++i) {
    int n = lane + 64*i;
    float x = X[3*n], y = X[3*n+1], z = X[3*n+2];
    float sx = x*x + y*y + z*z;
    float dot = cx*x + cy*y + cz*z;
    d2[n] = sc + sx - 2.0f*dot;
  }
  for (int it = 0; it < NK; ++it) {
    float bv = 3.0e38f; int bi = 0x7fffffff;
#pragma unroll 8
    for (int i = 0; i < NP/64; ++i) {
      int n = lane + 64*i;
      float v = d2[n];
      if (v < bv) { bv = v; bi = n; }
    }
#pragma unroll
    for (int off = 32; off; off >>= 1) {
      float ov = __shfl_xor(bv, off);
      int   oi = __shfl_xor(bi, off);
      if (ov < bv || (ov == bv && oi < bi)) { bv = ov; bi = oi; }
    }
    if (lane == 0) {
      d2[bi] = 3.3e38f;
      knn_idx[p*NK + it] = bi;
      float* g = gnorm + ((size_t)p*NK + it)*3;
      g[0] = X[3*bi]   - cx;
      g[1] = X[3*bi+1] - cy;
      g[2] = X[3*bi+2] - cz;
    }
  }
}

// ---------------------------------------------------------------- MLP layer 1
__global__ __launch_bounds__(256) void k_layer1(const float* __restrict__ points,
                                                const int* __restrict__ knn_idx,
                                                const float* __restrict__ gnorm,
                                                const float* __restrict__ w1,
                                                float* __restrict__ y,
                                                float* __restrict__ stats) {
  const int r0 = blockIdx.x * 64;
  const int t = threadIdx.x;
  __shared__ float Xs[64][69];
  __shared__ float Ws[64][69];
  __shared__ int nid[64];
  __shared__ float ps[4][64], pss[4][64];
  if (t < 64) nid[t] = knn_idx[r0 + t];
  __syncthreads();
  for (int idx = t; idx < 64*67; idx += 256) {
    int r = idx / 67, c = idx % 67;
    int row = r0 + r;
    float v;
    if (c < 3) v = gnorm[(size_t)row*3 + c];
    else {
      int bb = row >> 15;
      int n = nid[r];
      v = points[((size_t)bb*NP + n)*NCIN + (c-3)];
    }
    Xs[r][c] = v;
  }
  for (int idx = t; idx < 64*67; idx += 256) {
    int o = idx / 67, c = idx % 67;
    Ws[o][c] = w1[idx];
  }
  __syncthreads();
  const int col = t & 63;
  const int rb  = t >> 6;
  float s1 = 0.f, s2 = 0.f;
  for (int i = 0; i < 16; ++i) {
    int r = rb + 4*i;
    float acc = 0.f;
#pragma unroll
    for (int c = 0; c < 67; ++c) acc += Xs[r][c] * Ws[col][c];
    y[(size_t)(r0 + r)*64 + col] = acc;
    s1 += acc; s2 += acc*acc;
  }
  ps[rb][col] = s1; pss[rb][col] = s2;
  __syncthreads();
  if (t < 64) {
    float a = ps[0][t]+ps[1][t]+ps[2][t]+ps[3][t];
    float q = pss[0][t]+pss[1][t]+pss[2][t]+pss[3][t];
    atomicAdd(&stats[t], a);
    atomicAdd(&stats[64 + t], q);
  }
}

// ---------------------------------------------------------------- MLP layers 2/3
template <int COUT>
__global__ __launch_bounds__(256) void k_layer(const float* __restrict__ xin,
                                               const float* __restrict__ aff,
                                               const float* __restrict__ w,
                                               float* __restrict__ y,
                                               float* __restrict__ stats) {
  const int r0 = blockIdx.x * 64;
  const int t = threadIdx.x;
  __shared__ float Xs[64][65];
  __shared__ float Ws[COUT][65];
  __shared__ float sa[64], sb[64];
  constexpr int NTR = 256 / COUT;
  __shared__ float ps[NTR][COUT], pss[NTR][COUT];
  if (t < 64) { sa[t] = aff[t]; sb[t] = aff[64 + t]; }
  __syncthreads();
  for (int idx = t; idx < 64*64; idx += 256) {
    int r = idx >> 6, c = idx & 63;
    float v = xin[(size_t)r0*64 + idx];
    Xs[r][c] = fmaxf(sa[c]*v + sb[c], 0.0f);
  }
  for (int idx = t; idx < COUT*64; idx += 256) {
    int o = idx >> 6, c = idx & 63;
    Ws[o][c] = w[idx];
  }
  __syncthreads();
  const int col = t & (COUT-1);
  const int rb  = t / COUT;
  float s1 = 0.f, s2 = 0.f;
  for (int i = 0; i < 64/NTR; ++i) {
    int r = rb + NTR*i;
    float acc = 0.f;
#pragma unroll
    for (int c = 0; c < 64; ++c) acc += Xs[r][c] * Ws[col][c];
    y[(size_t)(r0 + r)*COUT + col] = acc;
    s1 += acc; s2 += acc*acc;
  }
  ps[rb][col] = s1; pss[rb][col] = s2;
  __syncthreads();
  if (t < COUT) {
    float a = 0.f, q = 0.f;
    for (int n = 0; n < NTR; ++n) { a += ps[n][t]; q += pss[n][t]; }
    atomicAdd(&stats[t], a);
    atomicAdd(&stats[COUT + t], q);
  }
}

// ---------------------------------------------------------------- BN stats -> affine
__global__ void k_finalize(const float* __restrict__ stats, const float* __restrict__ g,
                           const float* __restrict__ b, float* __restrict__ aff, int cout) {
  int t = threadIdx.x;
  if (t < cout) {
    const float inv = 1.0f / (float)NM;
    float m = stats[t] * inv;
    float var = stats[cout + t] * inv - m*m;
    float a = g[t] * rsqrtf(var + EPSF);
    aff[t] = a;
    aff[cout + t] = b[t] - m * a;
  }
}

// ---------------------------------------------------------------- pack weights (bf16 B-fragment layout)
__global__ __launch_bounds__(256) void k_pack(const float* __restrict__ ws,
                                              const float* __restrict__ wqkv,
                                              const float* __restrict__ wo,
                                              ushort_t* __restrict__ wpk) {
  int gid = blockIdx.x*256 + threadIdx.x;    // < 294912
  const float* src; int N_; int rem;
  if (gid < 163840)      { int mat = gid >> 14; rem = gid & 16383; src = ws  + (size_t)mat*16384; N_ = 128; }
  else if (gid < 262144) { int g2 = gid - 163840; int d = g2/49152; rem = g2 - d*49152; src = wqkv + (size_t)d*49152; N_ = 384; }
  else                   { int g3 = gid - 262144; int d = g3 >> 14; rem = g3 & 16383;  src = wo  + (size_t)d*16384; N_ = 128; }
  int NTN = N_ >> 4;
  int tile = rem >> 9, r = rem & 511;
  int tk = tile / NTN, tn = tile % NTN;
  int lane2 = r >> 3, jj = r & 7;
  int k = tk*32 + (lane2 >> 4)*8 + jj;
  int n = tn*16 + (lane2 & 15);
  wpk[gid] = f2b(src[(size_t)k*N_ + n]);
}

// ---------------------------------------------------------------- fused per-group v3
// persistent: hcurS 16K + hbS 8K + psisS 12.5K; scratch union 44160B -> 81536B total (2 blocks/CU)
__global__ __launch_bounds__(256) void k_group(
    const float* __restrict__ h3, const float* __restrict__ aff3,
    const float* __restrict__ gnorm,
    const ushort_t* __restrict__ wpk,
    const float* __restrict__ wb, const float* __restrict__ alpha,
    const float* __restrict__ ln1g, const float* __restrict__ ln1b,
    const float* __restrict__ ln2g, const float* __restrict__ ln2b,
    float* __restrict__ out) {
  const int p = blockIdx.x;
  const int t = threadIdx.x;
  const int lane = t & 63;
  const int w = t >> 6;

  __shared__ __align__(16) float    hcurS[NK*NC];      // fp32 activations
  __shared__ __align__(16) ushort_t hbS[NK*NC];        // bf16 mirror, XOR-swizzled
  __shared__ __align__(16) ushort_t psisS[5*32*40];    // psi_j row-major bf16
  __shared__ __align__(16) unsigned char scratch[44160];

  // psi-phase views
  float*    ddAF = (float*)scratch;                 // [32][33] (dd -> A in place)
  float*    pxF  = (float*)(scratch + 4224);        // 96
  float*    dinvF= (float*)(scratch + 4608);        // 32
  float*    sigF = (float*)(scratch + 4736);        // 8
  ushort_t* LbS  = (ushort_t*)(scratch + 4768);     // [32][40] bf16 L
  ushort_t* PmS  = (ushort_t*)(scratch + 7328);     // 3x[32][40] L^2,L^3,L^4
  // mix view
  ushort_t* HjS  = (ushort_t*)scratch;              // [128][40] col-major
  // u / proj view
  float*    uF   = (float*)scratch;                 // [32][128]
  // attention views
  ushort_t* qS   = (ushort_t*)scratch;              // [32][136]
  ushort_t* kS2  = (ushort_t*)(scratch + 8704);     // [32][136]
  ushort_t* vTS  = (ushort_t*)(scratch + 17408);    // [128][40]
  float*    scoF = (float*)(scratch + 27648);       // [32][129]

  // ---- init: px, pf -> hcur/hb
  if (t < 96) pxF[t] = gnorm[(size_t)p*96 + t];
  const float* h3p = h3 + (size_t)p*4096;
#pragma unroll
  for (int i = 0; i < 16; ++i) {
    int idx = t + 256*i;
    int c = idx & 127, row = idx >> 7;
    float v = fmaxf(aff3[c]*h3p[idx] + aff3[128+c], 0.f);
    hcurS[idx] = v;
    int ha = ((row << 8) + (c << 1)) ^ ((row & 7) << 4);
    hbS[ha >> 1] = f2b(v);
  }
  __syncthreads();
  // ---- dd
  for (int i = t; i < 1024; i += 256) {
    int k = i >> 5, l = i & 31;
    float dx = pxF[k*3]  -pxF[l*3];
    float dy = pxF[k*3+1]-pxF[l*3+1];
    float dz = pxF[k*3+2]-pxF[l*3+2];
    ddAF[k*33+l] = dx*dx + dy*dy + dz*dz;
  }
  __syncthreads();
  // ---- sigma
  float part = 0.f;
  for (int i = t; i < 1024; i += 256) part += sqrtf(ddAF[(i>>5)*33 + (i&31)] + 1e-12f);
#pragma unroll
  for (int off = 32; off; off >>= 1) part += __shfl_xor(part, off);
  if (lane == 0) sigF[w] = part;
  __syncthreads();
  if (t == 0) {
    float sg = (sigF[0]+sigF[1]+sigF[2]+sigF[3]) * (1.0f/1024.0f);
    sigF[4] = 2.0f*sg*sg + 1e-12f;
  }
  __syncthreads();
  const float denom = sigF[4];
  for (int i = t; i < 1024; i += 256) {
    int k = i >> 5, l = i & 31;
    ddAF[k*33+l] = expf(-ddAF[k*33+l] / denom);     // A
  }
  __syncthreads();
  if (t < 32) {
    float s = 0.f;
    for (int l = 0; l < 32; ++l) s += ddAF[t*33 + l];
    dinvF[t] = rsqrtf(s + 1e-12f);
  }
  __syncthreads();
  for (int i = t; i < 1024; i += 256) {             // Lb (L is symmetric)
    int k = i >> 5, l = i & 31;
    float v = -(dinvF[k] * ddAF[k*33+l] * dinvF[l]);
    if (k == l) v += 1.0f;
    LbS[k*40+l] = f2b(v);
  }
  __syncthreads();
  // ---- L^2, L^3, L^4 via MFMA (1 tile/wave; B uses symmetry of L)
  {
    int mi = w >> 1, ni = w & 1;
    int arow = (mi*16 + (lane & 15))*80 + ((lane >> 4) << 4);
    int brow = (ni*16 + (lane & 15))*80 + ((lane >> 4) << 4);
    bf16x8 bfr = *(const bf16x8*)((const char*)LbS + brow);
#pragma unroll
    for (int m = 2; m <= 4; ++m) {
      const ushort_t* Asrc = (m == 2) ? LbS : (PmS + (m-3)*1280);
      bf16x8 afr = *(const bf16x8*)((const char*)Asrc + arow);
      f32x4 z = {0.f,0.f,0.f,0.f};
      f32x4 pv = MFMA(afr, bfr, z);
      int rb2 = mi*16 + (lane >> 4)*4;
      int cl = ni*16 + (lane & 15);
#pragma unroll
      for (int r = 0; r < 4; ++r) PmS[(m-2)*1280 + (rb2+r)*40 + cl] = f2b(pv[r]);
      __syncthreads();
    }
  }
  // ---- psis: T_j = I + c1 L + c2 L^2 + c3 L^3 + c4 L^4 (all j fused)
  for (int i = t; i < 1024; i += 256) {
    int k = i >> 5, l = i & 31;
    float lb = b2f(LbS[k*40+l]);
    float p2 = b2f(PmS[k*40+l]);
    float p3 = b2f(PmS[1280 + k*40+l]);
    float p4 = b2f(PmS[2560 + k*40+l]);
    float diag = (k == l) ? 1.0f : 0.0f;
#pragma unroll
    for (int j = 0; j < NJ; ++j) {
      float sj = -0.05f * (float)(1 << j);
      float c2 = 0.5f*sj*sj;
      float c3 = c2*sj*(1.0f/3.0f);
      float c4 = c3*sj*0.25f;
      psisS[j*1280 + k*40 + l] = f2b(diag + sj*lb + c2*p2 + c3*p3 + c4*p4);
    }
  }
  __syncthreads();

  // ---- depth loop
  for (int d = 0; d < NDEPTH; ++d) {
    // ===== mix (registers) = sum_j alpha_j * psi_j @ (hcur @ Ws_j)
    f32x4 m00 = {0.f,0.f,0.f,0.f}, m01 = m00, m10 = m00, m11 = m00;
    for (int j = 0; j < NJ; ++j) {
      __syncthreads();                 // HjS free
      const ushort_t* Wp = wpk + (size_t)(d*NJ + j)*16384;
      const float alj = alpha[d*NJ + j];
#pragma unroll
      for (int tni = 0; tni < 2; ++tni) {
        int tn = 2*w + tni;
        f32x4 acc0 = {0.f,0.f,0.f,0.f}, acc1 = acc0;
#pragma unroll
        for (int tk = 0; tk < 4; ++tk) {
          bf16x8 b = *(const bf16x8*)(Wp + ((tk*8 + tn) << 9) + (lane << 3));
          int row0 = lane & 15;
          int ba0 = ((row0 << 8) + (tk << 6) + ((lane >> 4) << 4)) ^ ((row0 & 7) << 4);
          bf16x8 a0 = *(const bf16x8*)((const char*)hbS + ba0);
          acc0 = MFMA(a0, b, acc0);
          int row1 = 16 + (lane & 15);
          int ba1 = ((row1 << 8) + (tk << 6) + ((lane >> 4) << 4)) ^ ((row1 & 7) << 4);
          bf16x8 a1 = *(const bf16x8*)((const char*)hbS + ba1);
          acc1 = MFMA(a1, b, acc1);
        }
        int c = tn*16 + (lane & 15);
        int rbase = (lane >> 4) * 4;
#pragma unroll
        for (int r = 0; r < 4; ++r) {
          HjS[c*40 + rbase + r]      = f2b(alj * acc0[r]);
          HjS[c*40 + 16 + rbase + r] = f2b(alj * acc1[r]);
        }
      }
      __syncthreads();
      {
        const char* psj = (const char*)(psisS + j*1280);
        int koff = (lane >> 4) << 4;
        bf16x8 pa0 = *(const bf16x8*)(psj + (lane & 15)*80 + koff);
        bf16x8 pa1 = *(const bf16x8*)(psj + (16 + (lane & 15))*80 + koff);
        int n0 = 2*w*16 + (lane & 15);
        bf16x8 hb0 = *(const bf16x8*)((const char*)HjS + n0*80 + koff);
        bf16x8 hb1 = *(const bf16x8*)((const char*)HjS + (n0 + 16)*80 + koff);
        m00 = MFMA(pa0, hb0, m00);
        m01 = MFMA(pa0, hb1, m01);
        m10 = MFMA(pa1, hb0, m10);
        m11 = MFMA(pa1, hb1, m11);
      }
    }
    __syncthreads();
    // ===== u = hcur + relu(mix + wb) -> uF
    {
      int c0 = 32*w + (lane & 15);
      int c1 = c0 + 16;
      int r0 = (lane >> 4) * 4;
      float wb0 = wb[d*NC + c0], wb1 = wb[d*NC + c1];
#pragma unroll
      for (int r = 0; r < 4; ++r) {
        int row0 = r0 + r, row1 = 16 + r0 + r;
        uF[row0*NC + c0] = hcurS[row0*NC + c0] + fmaxf(m00[r] + wb0, 0.f);
        uF[row0*NC + c1] = hcurS[row0*NC + c1] + fmaxf(m01[r] + wb1, 0.f);
        uF[row1*NC + c0] = hcurS[row1*NC + c0] + fmaxf(m10[r] + wb0, 0.f);
        uF[row1*NC + c1] = hcurS[row1*NC + c1] + fmaxf(m11[r] + wb1, 0.f);
      }
    }
    __syncthreads();
    // ===== LN1: uF -> hcurS + hbS
    {
      const int k = t >> 3, e = t & 7;
      float s = 0.f;
#pragma unroll
      for (int ii = 0; ii < 16; ++ii) s += uF[k*NC + e + 8*ii];
      s += __shfl_xor(s,1); s += __shfl_xor(s,2); s += __shfl_xor(s,4);
      float mu = s * (1.0f/128.0f);
      float vs = 0.f;
#pragma unroll
      for (int ii = 0; ii < 16; ++ii) { float dx = uF[k*NC + e + 8*ii] - mu; vs += dx*dx; }
      vs += __shfl_xor(vs,1); vs += __shfl_xor(vs,2); vs += __shfl_xor(vs,4);
      float rs = rsqrtf(vs*(1.0f/128.0f) + EPSF);
#pragma unroll
      for (int ii = 0; ii < 16; ++ii) {
        int o = e + 8*ii;
        float hv = (uF[k*NC + o] - mu)*rs*ln1g[d*NC + o] + ln1b[d*NC + o];
        hcurS[k*NC + o] = hv;
        int ha = ((k << 8) + (o << 1)) ^ ((k & 7) << 4);
        hbS[ha >> 1] = f2b(hv);
      }
    }
    __syncthreads();
    // ===== attention, all heads fused
    const ushort_t* Wq = wpk + 163840 + (size_t)d*49152;
    // qkv: 48 tiles (2mi x 24tn), 12 per wave
#pragma unroll
    for (int ti = 0; ti < 12; ++ti) {
      int tile = w + 4*ti;
      int mi = (tile >= 24) ? 1 : 0;
      int tn = tile - 24*mi;
      int comp = tn >> 3;
      int cb = (tn & 7) * 16;
      f32x4 acc = {0.f,0.f,0.f,0.f};
#pragma unroll
      for (int tk = 0; tk < 4; ++tk) {
        bf16x8 b = *(const bf16x8*)(Wq + ((tk*24 + tn) << 9) + (lane << 3));
        int row = mi*16 + (lane & 15);
        int ba = ((row << 8) + (tk << 6) + ((lane >> 4) << 4)) ^ ((row & 7) << 4);
        bf16x8 a = *(const bf16x8*)((const char*)hbS + ba);
        acc = MFMA(a, b, acc);
      }
      int cl = cb + (lane & 15);
      int rb2 = mi*16 + (lane >> 4)*4;
      if (comp == 0) {
#pragma unroll
        for (int r = 0; r < 4; ++r) qS[(rb2+r)*136 + cl] = f2b(acc[r]);
      } else if (comp == 1) {
#pragma unroll
        for (int r = 0; r < 4; ++r) kS2[(rb2+r)*136 + cl] = f2b(acc[r]);
      } else {
#pragma unroll
        for (int r = 0; r < 4; ++r) vTS[cl*40 + rb2 + r] = f2b(acc[r]);
      }
    }
    __syncthreads();
    // scores: 16 tiles (4h x 2mi x 2ni), 4 per wave
#pragma unroll
    for (int ti = 0; ti < 4; ++ti) {
      int tile = w + 4*ti;
      int h = tile >> 2, mi = (tile >> 1) & 1, ni = tile & 1;
      int koff = h*64 + ((lane >> 4) << 4);
      bf16x8 qa = *(const bf16x8*)((const char*)qS  + (mi*16 + (lane & 15))*272 + koff);
      bf16x8 kb = *(const bf16x8*)((const char*)kS2 + (ni*16 + (lane & 15))*272 + koff);
      f32x4 z = {0.f,0.f,0.f,0.f};
      f32x4 sc = MFMA(qa, kb, z);
      int colL = h*32 + ni*16 + (lane & 15);
      int rb2 = mi*16 + (lane >> 4)*4;
#pragma unroll
      for (int r = 0; r < 4; ++r) scoF[(rb2 + r)*129 + colL] = sc[r] * 0.17677669529663687f;
    }
    __syncthreads();
    // softmax: 128 (row,head) units, 2 threads each; att -> qS (reuse)
    {
      int unit = t >> 1, e = t & 1;
      int row = unit & 31, h = unit >> 5;
      const float* srow = scoF + row*129 + h*32 + e*16;
      float v[16];
      float mx = -3.4e38f;
#pragma unroll
      for (int q = 0; q < 16; ++q) { v[q] = srow[q]; mx = fmaxf(mx, v[q]); }
      mx = fmaxf(mx, __shfl_xor(mx, 1));
      float s = 0.f;
#pragma unroll
      for (int q = 0; q < 16; ++q) { v[q] = expf(v[q] - mx); s += v[q]; }
      s += __shfl_xor(s, 1);
      float inv = 1.0f / s;
      ushort_t* arow = qS + row*136 + h*32 + e*16;
#pragma unroll
      for (int q = 0; q < 16; ++q) arow[q] = f2b(v[q] * inv);
    }
    __syncthreads();
    // PV: 16 tiles, 4 per wave; write o directly into hbS (bf16, swizzled)
#pragma unroll
    for (int ti = 0; ti < 4; ++ti) {
      int tile = w + 4*ti;
      int h = tile >> 2, mi = (tile >> 1) & 1, ni = tile & 1;
      bf16x8 aa = *(const bf16x8*)((const char*)qS + (mi*16 + (lane & 15))*272 + h*64 + ((lane >> 4) << 4));
      bf16x8 vb = *(const bf16x8*)((const char*)vTS + (h*32 + ni*16 + (lane & 15))*80 + ((lane >> 4) << 4));
      f32x4 z = {0.f,0.f,0.f,0.f};
      f32x4 ov = MFMA(aa, vb, z);
      int col = h*32 + ni*16 + (lane & 15);
      int rb2 = mi*16 + (lane >> 4)*4;
#pragma unroll
      for (int r = 0; r < 4; ++r) {
        int row = rb2 + r;
        int ha = ((row << 8) + (col << 1)) ^ ((row & 7) << 4);
        hbS[ha >> 1] = f2b(ov[r]);
      }
    }
    __syncthreads();
    // ===== proj: o @ Wo; u2 = hcur + proj -> uF
    const ushort_t* Wop = wpk + 262144 + (size_t)d*16384;
#pragma unroll
    for (int tni = 0; tni < 2; ++tni) {
      int tn = 2*w + tni;
      f32x4 acc0 = {0.f,0.f,0.f,0.f}, acc1 = acc0;
#pragma unroll
      for (int tk = 0; tk < 4; ++tk) {
        bf16x8 b = *(const bf16x8*)(Wop + ((tk*8 + tn) << 9) + (lane << 3));
        int row0 = lane & 15;
        int ba0 = ((row0 << 8) + (tk << 6) + ((lane >> 4) << 4)) ^ ((row0 & 7) << 4);
        bf16x8 a0 = *(const bf16x8*)((const char*)hbS + ba0);
        acc0 = MFMA(a0, b, acc0);
        int row1 = 16 + (lane & 15);
        int ba1 = ((row1 << 8) + (tk << 6) + ((lane >> 4) << 4)) ^ ((row1 & 7) << 4);
        bf16x8 a1 = *(const bf16x8*)((const char*)hbS + ba1);
        acc1 = MFMA(a1, b, acc1);
      }
      int c = tn*16 + (lane & 15);
      int rb2 = (lane >> 4)*4;
#pragma unroll
      for (int r = 0; r < 4; ++r) {
        uF[(rb2 + r)*NC + c]      = hcurS[(rb2 + r)*NC + c]      + acc0[r];
        uF[(16 + rb2 + r)*NC + c] = hcurS[(16 + rb2 + r)*NC + c] + acc1[r];
      }
    }
    __syncthreads();
    // ===== LN2: uF -> hcurS + hbS
    {
      const int k = t >> 3, e = t & 7;
      float s = 0.f;
#pragma unroll
      for (int ii = 0; ii < 16; ++ii) s += uF[k*NC + e + 8*ii];
      s += __shfl_xor(s,1); s += __shfl_xor(s,2); s += __shfl_xor(s,4);
      float mu = s * (1.0f/128.0f);
      float vs = 0.f;
#pragma unroll
      for (int ii = 0; ii < 16; ++ii) { float dx = uF[k*NC + e + 8*ii] - mu; vs += dx*dx; }
      vs += __shfl_xor(vs,1); vs += __shfl_xor(vs,2); vs += __shfl_xor(vs,4);
      float rs = rsqrtf(vs*(1.0f/128.0f) + EPSF);
#pragma unroll
      for (int ii = 0; ii < 16; ++ii) {
        int o = e + 8*ii;
        float hv = (uF[k*NC + o] - mu)*rs*ln2g[d*NC + o] + ln2b[d*NC + o];
        hcurS[k*NC + o] = hv;
        int ha = ((k << 8) + (o << 1)) ^ ((k & 7) << 4);
        hbS[ha >> 1] = f2b(hv);
      }
    }
    __syncthreads();
  }
  // ---- maxpool over K
  if (t < NC) {
    float m = hcurS[t];
    for (int k = 1; k < NK; ++k) m = fmaxf(m, hcurS[k*NC + t]);
    out[(size_t)p*NC + t] = m;
  }
}

// ---------------------------------------------------------------- launcher
extern "C" void kernel_launch(void* const* d_in, const int* in_sizes, int n_in,
                              void* d_out, int out_size, void* d_ws, size_t ws_size,
                              hipStream_t stream) {
  const float* xyz    = (const float*)d_in[0];
  const float* points = (const float*)d_in[1];
  const float* w1     = (const float*)d_in[2];
  const float* g1     = (const float*)d_in[3];
  const float* b1     = (const float*)d_in[4];
  const float* w2     = (const float*)d_in[5];
  const float* g2     = (const float*)d_in[6];
  const float* b2     = (const float*)d_in[7];
  const float* w3     = (const float*)d_in[8];
  const float* g3     = (const float*)d_in[9];
  const float* b3     = (const float*)d_in[10];
  const float* wsW    = (const float*)d_in[11];
  const float* wb     = (const float*)d_in[12];
  const float* alpha  = (const float*)d_in[13];
  const float* wqkv   = (const float*)d_in[14];
  const float* wo     = (const float*)d_in[15];
  const float* ln1g   = (const float*)d_in[16];
  const float* ln1b   = (const float*)d_in[17];
  const float* ln2g   = (const float*)d_in[18];
  const float* ln2b   = (const float*)d_in[19];
  float* outp = (float*)d_out;

  float* wsf   = (float*)d_ws;
  float* gnorm = wsf;                        // 786432 f
  float* stats = wsf + 786432;               // 768 f
  float* aff   = wsf + 787200;               // 768 f
  int*   knn   = (int*)(wsf + 787968);       // 262144 i  (reused as wpk after k_layer1)
  ushort_t* wpk = (ushort_t*)(wsf + 787968); // 294912 bf16
  float* h2    = wsf + 1050112;              // 16777216 f
  float* hX    = wsf + 17827328;             // 33554432 f

  hipMemsetAsync(stats, 0, 768*sizeof(float), stream);
  k_fps<<<NB, 256, 0, stream>>>(xyz, outp);
  k_knn<<<NPTS, 64, 0, stream>>>(xyz, outp, knn, gnorm);
  k_layer1<<<NM/64, 256, 0, stream>>>(points, knn, gnorm, w1, hX, stats);
  k_pack<<<294912/256, 256, 0, stream>>>(wsW, wqkv, wo, wpk);
  k_finalize<<<1, 128, 0, stream>>>(stats, g1, b1, aff, 64);
  k_layer<64><<<NM/64, 256, 0, stream>>>(hX, aff, w2, h2, stats + 256);
  k_finalize<<<1, 128, 0, stream>>>(stats + 256, g2, b2, aff + 256, 64);
  k_layer<128><<<NM/64, 256, 0, stream>>>(h2, aff + 256, w3, hX, stats + 512);
  k_finalize<<<1, 128, 0, stream>>>(stats + 512, g3, b3, aff + 512, 128);
  k_group<<<NPTS, 256, 0, stream>>>(hX, aff + 512, gnorm, wpk, wb, alpha,
                                    ln1g, ln1b, ln2g, ln2b, outp + (size_t)NB*NS*3);
}

// Round 6
// 1833.308 us; speedup vs baseline: 8.4628x; 1.1012x over previous
//
#include <hip/hip_runtime.h>
#include <math.h>

#define NB 8
#define NP 4096
#define NCIN 64
#define NS 1024
#define NK 32
#define NC 128
#define NJ 5
#define NDEPTH 2
#define NH 4
#define NPTS (NB*NS)       /* 8192 groups */
#define NM (NPTS*NK)       /* 262144 rows */
#define EPSF 1e-5f

typedef float f32x4 __attribute__((ext_vector_type(4)));
typedef short bf16x8 __attribute__((ext_vector_type(8)));
typedef unsigned short ushort_t;
typedef unsigned long long u64;

#define MFMA(a,b,c) __builtin_amdgcn_mfma_f32_16x16x32_bf16(a,b,c,0,0,0)

__device__ __forceinline__ ushort_t f2b(float f) {
  unsigned int u = __float_as_uint(f);
  u = (u + 0x7fffu + ((u >> 16) & 1u)) >> 16;
  return (ushort_t)u;
}
__device__ __forceinline__ float b2f(ushort_t h) {
  unsigned int u = ((unsigned int)h) << 16;
  return __uint_as_float(u);
}

// ---------------------------------------------------------------- FPS
// DPP wave-64 max reduce (VALU pipe) instead of ds_bpermute butterfly (LDS pipe).
// row_shr 1,2,4,8 -> lane15/31/47/63 hold row maxes; row_bcast15 -> lane31/63
// combine; row_bcast31 -> lane63 = wave max. bound_ctrl=true gives 0 on invalid
// lanes = identity (all packs > 0 since lo = ~idx != 0).
#define DPPMAX(CTRL) { \
  unsigned lo2 = (unsigned)__builtin_amdgcn_update_dpp(0, (int)(unsigned)best, CTRL, 0xf, 0xf, true); \
  unsigned hi2 = (unsigned)__builtin_amdgcn_update_dpp(0, (int)(unsigned)(best >> 32), CTRL, 0xf, 0xf, true); \
  u64 o = ((u64)hi2 << 32) | lo2; \
  if (o > best) best = o; }

__global__ __launch_bounds__(256) void k_fps(const float* __restrict__ xyz,
                                             float* __restrict__ newxyz) {
  const int b = blockIdx.x;
  const int t = threadIdx.x;
  const int lane = t & 63;
  const int w = t >> 6;
  __shared__ float Xl[NP*3];
  __shared__ float cenL[NS*3];
  __shared__ u64 slot[2][4];
  const float* X = xyz + (size_t)b * NP * 3;
  for (int i = t; i < NP*3; i += 256) Xl[i] = X[i];
  __syncthreads();
  float px[16], py[16], pz[16], dist[16];
  unsigned inv[16];
#pragma unroll
  for (int i = 0; i < 16; ++i) {
    int n = t + 256*i;
    px[i] = Xl[3*n]; py[i] = Xl[3*n+1]; pz[i] = Xl[3*n+2];
    dist[i] = 1e10f;
    inv[i] = ~(unsigned)n;               // pack low word, per-lane constant
  }
  int far = 0;
  for (int s = 0; s < NS; ++s) {
    float cx = Xl[3*far], cy = Xl[3*far+1], cz = Xl[3*far+2];
    if (t == 0) { cenL[3*s] = cx; cenL[3*s+1] = cy; cenL[3*s+2] = cz; }
    u64 pk[16];
#pragma unroll
    for (int i = 0; i < 16; ++i) {
      float dx = px[i]-cx, dy = py[i]-cy, dz = pz[i]-cz;
      float d = fmaf(dx,dx, fmaf(dy,dy, dz*dz));
      float nd = fminf(dist[i], d);
      dist[i] = nd;
      pk[i] = ((u64)__float_as_uint(nd) << 32) | inv[i];
    }
    // depth-4 in-lane tree (ascending index order preserved by strict >)
#pragma unroll
    for (int st = 1; st < 16; st <<= 1)
#pragma unroll
      for (int i = 0; i < 16; i += 2*st)
        pk[i] = pk[i+st] > pk[i] ? pk[i+st] : pk[i];
    u64 best = pk[0];
    DPPMAX(0x111)  // row_shr:1
    DPPMAX(0x112)  // row_shr:2
    DPPMAX(0x114)  // row_shr:4
    DPPMAX(0x118)  // row_shr:8
    DPPMAX(0x142)  // row_bcast15
    DPPMAX(0x143)  // row_bcast31  -> lane 63 holds wave max
    if (lane == 63) slot[s&1][w] = best;
    __syncthreads();
    const u64* sl = slot[s&1];
    u64 s0 = sl[0], s1 = sl[1], s2 = sl[2], s3 = sl[3];
    s0 = s1 > s0 ? s1 : s0;
    s2 = s3 > s2 ? s3 : s2;
    s0 = s2 > s0 ? s2 : s0;
    far = (int)(~(unsigned)s0);
  }
  __syncthreads();
  float* o = newxyz + (size_t)b * NS * 3;
  for (int i = t; i < NS*3; i += 256) o[i] = cenL[i];
}

// ---------------------------------------------------------------- KNN
__global__ __launch_bounds__(64) void k_knn(const float* __restrict__ xyz,
                                            const float* __restrict__ newxyz,
                                            int* __restrict__ knn_idx,
                                            float* __restrict__ gnorm) {
  const int p = blockIdx.x;
  const int b = p >> 10;
  const int lane = threadIdx.x;
  const float* X = xyz + (size_t)b * NP * 3;
  __shared__ float d2[NP];
  float cx = newxyz[3*p], cy = newxyz[3*p+1], cz = newxyz[3*p+2];
  float sc = cx*cx + cy*cy + cz*cz;
#pragma unroll 4
  for (int i = 0; i < NP/64; ++i) {
    int n = lane + 64*i;
    float x = X[3*n], y = X[3*n+1], z = X[3*n+2];
    float sx = x*x + y*y + z*z;
    float dot = cx*x + cy*y + cz*z;
    d2[n] = sc + sx - 2.0f*dot;
  }
  for (int it = 0; it < NK; ++it) {
    float bv = 3.0e38f; int bi = 0x7fffffff;
#pragma unroll 8
    for (int i = 0; i < NP/64; ++i) {
      int n = lane + 64*i;
      float v = d2[n];
      if (v < bv) { bv = v; bi = n; }
    }
#pragma unroll
    for (int off = 32; off; off >>= 1) {
      float ov = __shfl_xor(bv, off);
      int   oi = __shfl_xor(bi, off);
      if (ov < bv || (ov == bv && oi < bi)) { bv = ov; bi = oi; }
    }
    if (lane == 0) {
      d2[bi] = 3.3e38f;
      knn_idx[p*NK + it] = bi;
      float* g = gnorm + ((size_t)p*NK + it)*3;
      g[0] = X[3*bi]   - cx;
      g[1] = X[3*bi+1] - cy;
      g[2] = X[3*bi+2] - cz;
    }
  }
}

// ---------------------------------------------------------------- MLP layer 1
__global__ __launch_bounds__(256) void k_layer1(const float* __restrict__ points,
                                                const int* __restrict__ knn_idx,
                                                const float* __restrict__ gnorm,
                                                const float* __restrict__ w1,
                                                float* __restrict__ y,
                                                float* __restrict__ stats) {
  const int r0 = blockIdx.x * 64;
  const int t = threadIdx.x;
  __shared__ float Xs[64][69];
  __shared__ float Ws[64][69];
  __shared__ int nid[64];
  __shared__ float ps[4][64], pss[4][64];
  if (t < 64) nid[t] = knn_idx[r0 + t];
  __syncthreads();
  for (int idx = t; idx < 64*67; idx += 256) {
    int r = idx / 67, c = idx % 67;
    int row = r0 + r;
    float v;
    if (c < 3) v = gnorm[(size_t)row*3 + c];
    else {
      int bb = row >> 15;
      int n = nid[r];
      v = points[((size_t)bb*NP + n)*NCIN + (c-3)];
    }
    Xs[r][c] = v;
  }
  for (int idx = t; idx < 64*67; idx += 256) {
    int o = idx / 67, c = idx % 67;
    Ws[o][c] = w1[idx];
  }
  __syncthreads();
  const int col = t & 63;
  const int rb  = t >> 6;
  float s1 = 0.f, s2 = 0.f;
  for (int i = 0; i < 16; ++i) {
    int r = rb + 4*i;
    float acc = 0.f;
#pragma unroll
    for (int c = 0; c < 67; ++c) acc += Xs[r][c] * Ws[col][c];
    y[(size_t)(r0 + r)*64 + col] = acc;
    s1 += acc; s2 += acc*acc;
  }
  ps[rb][col] = s1; pss[rb][col] = s2;
  __syncthreads();
  if (t < 64) {
    float a = ps[0][t]+ps[1][t]+ps[2][t]+ps[3][t];
    float q = pss[0][t]+pss[1][t]+pss[2][t]+pss[3][t];
    atomicAdd(&stats[t], a);
    atomicAdd(&stats[64 + t], q);
  }
}

// ---------------------------------------------------------------- MLP layers 2/3
template <int COUT>
__global__ __launch_bounds__(256) void k_layer(const float* __restrict__ xin,
                                               const float* __restrict__ aff,
                                               const float* __restrict__ w,
                                               float* __restrict__ y,
                                               float* __restrict__ stats) {
  const int r0 = blockIdx.x * 64;
  const int t = threadIdx.x;
  __shared__ float Xs[64][65];
  __shared__ float Ws[COUT][65];
  __shared__ float sa[64], sb[64];
  constexpr int NTR = 256 / COUT;
  __shared__ float ps[NTR][COUT], pss[NTR][COUT];
  if (t < 64) { sa[t] = aff[t]; sb[t] = aff[64 + t]; }
  __syncthreads();
  for (int idx = t; idx < 64*64; idx += 256) {
    int r = idx >> 6, c = idx & 63;
    float v = xin[(size_t)r0*64 + idx];
    Xs[r][c] = fmaxf(sa[c]*v + sb[c], 0.0f);
  }
  for (int idx = t; idx < COUT*64; idx += 256) {
    int o = idx >> 6, c = idx & 63;
    Ws[o][c] = w[idx];
  }
  __syncthreads();
  const int col = t & (COUT-1);
  const int rb  = t / COUT;
  float s1 = 0.f, s2 = 0.f;
  for (int i = 0; i < 64/NTR; ++i) {
    int r = rb + NTR*i;
    float acc = 0.f;
#pragma unroll
    for (int c = 0; c < 64; ++c) acc += Xs[r][c] * Ws[col][c];
    y[(size_t)(r0 + r)*COUT + col] = acc;
    s1 += acc; s2 += acc*acc;
  }
  ps[rb][col] = s1; pss[rb][col] = s2;
  __syncthreads();
  if (t < COUT) {
    float a = 0.f, q = 0.f;
    for (int n = 0; n < NTR; ++n) { a += ps[n][t]; q += pss[n][t]; }
    atomicAdd(&stats[t], a);
    atomicAdd(&stats[COUT + t], q);
  }
}

// ---------------------------------------------------------------- BN stats -> affine
__global__ void k_finalize(const float* __restrict__ stats, const float* __restrict__ g,
                           const float* __restrict__ b, float* __restrict__ aff, int cout) {
  int t = threadIdx.x;
  if (t < cout) {
    const float inv = 1.0f / (float)NM;
    float m = stats[t] * inv;
    float var = stats[cout + t] * inv - m*m;
    float a = g[t] * rsqrtf(var + EPSF);
    aff[t] = a;
    aff[cout + t] = b[t] - m * a;
  }
}

// ---------------------------------------------------------------- pack weights (bf16 B-fragment layout)
__global__ __launch_bounds__(256) void k_pack(const float* __restrict__ ws,
                                              const float* __restrict__ wqkv,
                                              const float* __restrict__ wo,
                                              ushort_t* __restrict__ wpk) {
  int gid = blockIdx.x*256 + threadIdx.x;    // < 294912
  const float* src; int N_; int rem;
  if (gid < 163840)      { int mat = gid >> 14; rem = gid & 16383; src = ws  + (size_t)mat*16384; N_ = 128; }
  else if (gid < 262144) { int g2 = gid - 163840; int d = g2/49152; rem = g2 - d*49152; src = wqkv + (size_t)d*49152; N_ = 384; }
  else                   { int g3 = gid - 262144; int d = g3 >> 14; rem = g3 & 16383;  src = wo  + (size_t)d*16384; N_ = 128; }
  int NTN = N_ >> 4;
  int tile = rem >> 9, r = rem & 511;
  int tk = tile / NTN, tn = tile % NTN;
  int lane2 = r >> 3, jj = r & 7;
  int k = tk*32 + (lane2 >> 4)*8 + jj;
  int n = tn*16 + (lane2 & 15);
  wpk[gid] = f2b(src[(size_t)k*N_ + n]);
}

// ---------------------------------------------------------------- fused per-group v3
__global__ __launch_bounds__(256) void k_group(
    const float* __restrict__ h3, const float* __restrict__ aff3,
    const float* __restrict__ gnorm,
    const ushort_t* __restrict__ wpk,
    const float* __restrict__ wb, const float* __restrict__ alpha,
    const float* __restrict__ ln1g, const float* __restrict__ ln1b,
    const float* __restrict__ ln2g, const float* __restrict__ ln2b,
    float* __restrict__ out) {
  const int p = blockIdx.x;
  const int t = threadIdx.x;
  const int lane = t & 63;
  const int w = t >> 6;

  __shared__ __align__(16) float    hcurS[NK*NC];
  __shared__ __align__(16) ushort_t hbS[NK*NC];
  __shared__ __align__(16) ushort_t psisS[5*32*40];
  __shared__ __align__(16) unsigned char scratch[44160];

  float*    ddAF = (float*)scratch;
  float*    pxF  = (float*)(scratch + 4224);
  float*    dinvF= (float*)(scratch + 4608);
  float*    sigF = (float*)(scratch + 4736);
  ushort_t* LbS  = (ushort_t*)(scratch + 4768);
  ushort_t* PmS  = (ushort_t*)(scratch + 7328);
  ushort_t* HjS  = (ushort_t*)scratch;
  float*    uF   = (float*)scratch;
  ushort_t* qS   = (ushort_t*)scratch;
  ushort_t* kS2  = (ushort_t*)(scratch + 8704);
  ushort_t* vTS  = (ushort_t*)(scratch + 17408);
  float*    scoF = (float*)(scratch + 27648);

  if (t < 96) pxF[t] = gnorm[(size_t)p*96 + t];
  const float* h3p = h3 + (size_t)p*4096;
#pragma unroll
  for (int i = 0; i < 16; ++i) {
    int idx = t + 256*i;
    int c = idx & 127, row = idx >> 7;
    float v = fmaxf(aff3[c]*h3p[idx] + aff3[128+c], 0.f);
    hcurS[idx] = v;
    int ha = ((row << 8) + (c << 1)) ^ ((row & 7) << 4);
    hbS[ha >> 1] = f2b(v);
  }
  __syncthreads();
  for (int i = t; i < 1024; i += 256) {
    int k = i >> 5, l = i & 31;
    float dx = pxF[k*3]  -pxF[l*3];
    float dy = pxF[k*3+1]-pxF[l*3+1];
    float dz = pxF[k*3+2]-pxF[l*3+2];
    ddAF[k*33+l] = dx*dx + dy*dy + dz*dz;
  }
  __syncthreads();
  float part = 0.f;
  for (int i = t; i < 1024; i += 256) part += sqrtf(ddAF[(i>>5)*33 + (i&31)] + 1e-12f);
#pragma unroll
  for (int off = 32; off; off >>= 1) part += __shfl_xor(part, off);
  if (lane == 0) sigF[w] = part;
  __syncthreads();
  if (t == 0) {
    float sg = (sigF[0]+sigF[1]+sigF[2]+sigF[3]) * (1.0f/1024.0f);
    sigF[4] = 2.0f*sg*sg + 1e-12f;
  }
  __syncthreads();
  const float denom = sigF[4];
  for (int i = t; i < 1024; i += 256) {
    int k = i >> 5, l = i & 31;
    ddAF[k*33+l] = expf(-ddAF[k*33+l] / denom);
  }
  __syncthreads();
  if (t < 32) {
    float s = 0.f;
    for (int l = 0; l < 32; ++l) s += ddAF[t*33 + l];
    dinvF[t] = rsqrtf(s + 1e-12f);
  }
  __syncthreads();
  for (int i = t; i < 1024; i += 256) {
    int k = i >> 5, l = i & 31;
    float v = -(dinvF[k] * ddAF[k*33+l] * dinvF[l]);
    if (k == l) v += 1.0f;
    LbS[k*40+l] = f2b(v);
  }
  __syncthreads();
  {
    int mi = w >> 1, ni = w & 1;
    int arow = (mi*16 + (lane & 15))*80 + ((lane >> 4) << 4);
    int brow = (ni*16 + (lane & 15))*80 + ((lane >> 4) << 4);
    bf16x8 bfr = *(const bf16x8*)((const char*)LbS + brow);
#pragma unroll
    for (int m = 2; m <= 4; ++m) {
      const ushort_t* Asrc = (m == 2) ? LbS : (PmS + (m-3)*1280);
      bf16x8 afr = *(const bf16x8*)((const char*)Asrc + arow);
      f32x4 z = {0.f,0.f,0.f,0.f};
      f32x4 pv = MFMA(afr, bfr, z);
      int rb2 = mi*16 + (lane >> 4)*4;
      int cl = ni*16 + (lane & 15);
#pragma unroll
      for (int r = 0; r < 4; ++r) PmS[(m-2)*1280 + (rb2+r)*40 + cl] = f2b(pv[r]);
      __syncthreads();
    }
  }
  for (int i = t; i < 1024; i += 256) {
    int k = i >> 5, l = i & 31;
    float lb = b2f(LbS[k*40+l]);
    float p2 = b2f(PmS[k*40+l]);
    float p3 = b2f(PmS[1280 + k*40+l]);
    float p4 = b2f(PmS[2560 + k*40+l]);
    float diag = (k == l) ? 1.0f : 0.0f;
#pragma unroll
    for (int j = 0; j < NJ; ++j) {
      float sj = -0.05f * (float)(1 << j);
      float c2 = 0.5f*sj*sj;
      float c3 = c2*sj*(1.0f/3.0f);
      float c4 = c3*sj*0.25f;
      psisS[j*1280 + k*40 + l] = f2b(diag + sj*lb + c2*p2 + c3*p3 + c4*p4);
    }
  }
  __syncthreads();

  for (int d = 0; d < NDEPTH; ++d) {
    f32x4 m00 = {0.f,0.f,0.f,0.f}, m01 = m00, m10 = m00, m11 = m00;
    for (int j = 0; j < NJ; ++j) {
      __syncthreads();
      const ushort_t* Wp = wpk + (size_t)(d*NJ + j)*16384;
      const float alj = alpha[d*NJ + j];
#pragma unroll
      for (int tni = 0; tni < 2; ++tni) {
        int tn = 2*w + tni;
        f32x4 acc0 = {0.f,0.f,0.f,0.f}, acc1 = acc0;
#pragma unroll
        for (int tk = 0; tk < 4; ++tk) {
          bf16x8 b = *(const bf16x8*)(Wp + ((tk*8 + tn) << 9) + (lane << 3));
          int row0 = lane & 15;
          int ba0 = ((row0 << 8) + (tk << 6) + ((lane >> 4) << 4)) ^ ((row0 & 7) << 4);
          bf16x8 a0 = *(const bf16x8*)((const char*)hbS + ba0);
          acc0 = MFMA(a0, b, acc0);
          int row1 = 16 + (lane & 15);
          int ba1 = ((row1 << 8) + (tk << 6) + ((lane >> 4) << 4)) ^ ((row1 & 7) << 4);
          bf16x8 a1 = *(const bf16x8*)((const char*)hbS + ba1);
          acc1 = MFMA(a1, b, acc1);
        }
        int c = tn*16 + (lane & 15);
        int rbase = (lane >> 4) * 4;
#pragma unroll
        for (int r = 0; r < 4; ++r) {
          HjS[c*40 + rbase + r]      = f2b(alj * acc0[r]);
          HjS[c*40 + 16 + rbase + r] = f2b(alj * acc1[r]);
        }
      }
      __syncthreads();
      {
        const char* psj = (const char*)(psisS + j*1280);
        int koff = (lane >> 4) << 4;
        bf16x8 pa0 = *(const bf16x8*)(psj + (lane & 15)*80 + koff);
        bf16x8 pa1 = *(const bf16x8*)(psj + (16 + (lane & 15))*80 + koff);
        int n0 = 2*w*16 + (lane & 15);
        bf16x8 hb0 = *(const bf16x8*)((const char*)HjS + n0*80 + koff);
        bf16x8 hb1 = *(const bf16x8*)((const char*)HjS + (n0 + 16)*80 + koff);
        m00 = MFMA(pa0, hb0, m00);
        m01 = MFMA(pa0, hb1, m01);
        m10 = MFMA(pa1, hb0, m10);
        m11 = MFMA(pa1, hb1, m11);
      }
    }
    __syncthreads();
    {
      int c0 = 32*w + (lane & 15);
      int c1 = c0 + 16;
      int r0 = (lane >> 4) * 4;
      float wb0 = wb[d*NC + c0], wb1 = wb[d*NC + c1];
#pragma unroll
      for (int r = 0; r < 4; ++r) {
        int row0 = r0 + r, row1 = 16 + r0 + r;
        uF[row0*NC + c0] = hcurS[row0*NC + c0] + fmaxf(m00[r] + wb0, 0.f);
        uF[row0*NC + c1] = hcurS[row0*NC + c1] + fmaxf(m01[r] + wb1, 0.f);
        uF[row1*NC + c0] = hcurS[row1*NC + c0] + fmaxf(m10[r] + wb0, 0.f);
        uF[row1*NC + c1] = hcurS[row1*NC + c1] + fmaxf(m11[r] + wb1, 0.f);
      }
    }
    __syncthreads();
    {
      const int k = t >> 3, e = t & 7;
      float s = 0.f;
#pragma unroll
      for (int ii = 0; ii < 16; ++ii) s += uF[k*NC + e + 8*ii];
      s += __shfl_xor(s,1); s += __shfl_xor(s,2); s += __shfl_xor(s,4);
      float mu = s * (1.0f/128.0f);
      float vs = 0.f;
#pragma unroll
      for (int ii = 0; ii < 16; ++ii) { float dx = uF[k*NC + e + 8*ii] - mu; vs += dx*dx; }
      vs += __shfl_xor(vs,1); vs += __shfl_xor(vs,2); vs += __shfl_xor(vs,4);
      float rs = rsqrtf(vs*(1.0f/128.0f) + EPSF);
#pragma unroll
      for (int ii = 0; ii < 16; ++ii) {
        int o = e + 8*ii;
        float hv = (uF[k*NC + o] - mu)*rs*ln1g[d*NC + o] + ln1b[d*NC + o];
        hcurS[k*NC + o] = hv;
        int ha = ((k << 8) + (o << 1)) ^ ((k & 7) << 4);
        hbS[ha >> 1] = f2b(hv);
      }
    }
    __syncthreads();
    const ushort_t* Wq = wpk + 163840 + (size_t)d*49152;
#pragma unroll
    for (int ti = 0; ti < 12; ++ti) {
      int tile = w + 4*ti;
      int mi = (tile >= 24) ? 1 : 0;
      int tn = tile - 24*mi;
      int comp = tn >> 3;
      int cb = (tn & 7) * 16;
      f32x4 acc = {0.f,0.f,0.f,0.f};
#pragma unroll
      for (int tk = 0; tk < 4; ++tk) {
        bf16x8 b = *(const bf16x8*)(Wq + ((tk*24 + tn) << 9) + (lane << 3));
        int row = mi*16 + (lane & 15);
        int ba = ((row << 8) + (tk << 6) + ((lane >> 4) << 4)) ^ ((row & 7) << 4);
        bf16x8 a = *(const bf16x8*)((const char*)hbS + ba);
        acc = MFMA(a, b, acc);
      }
      int cl = cb + (lane & 15);
      int rb2 = mi*16 + (lane >> 4)*4;
      if (comp == 0) {
#pragma unroll
        for (int r = 0; r < 4; ++r) qS[(rb2+r)*136 + cl] = f2b(acc[r]);
      } else if (comp == 1) {
#pragma unroll
        for (int r = 0; r < 4; ++r) kS2[(rb2+r)*136 + cl] = f2b(acc[r]);
      } else {
#pragma unroll
        for (int r = 0; r < 4; ++r) vTS[cl*40 + rb2 + r] = f2b(acc[r]);
      }
    }
    __syncthreads();
#pragma unroll
    for (int ti = 0; ti < 4; ++ti) {
      int tile = w + 4*ti;
      int h = tile >> 2, mi = (tile >> 1) & 1, ni = tile & 1;
      int koff = h*64 + ((lane >> 4) << 4);
      bf16x8 qa = *(const bf16x8*)((const char*)qS  + (mi*16 + (lane & 15))*272 + koff);
      bf16x8 kb = *(const bf16x8*)((const char*)kS2 + (ni*16 + (lane & 15))*272 + koff);
      f32x4 z = {0.f,0.f,0.f,0.f};
      f32x4 sc = MFMA(qa, kb, z);
      int colL = h*32 + ni*16 + (lane & 15);
      int rb2 = mi*16 + (lane >> 4)*4;
#pragma unroll
      for (int r = 0; r < 4; ++r) scoF[(rb2 + r)*129 + colL] = sc[r] * 0.17677669529663687f;
    }
    __syncthreads();
    {
      int unit = t >> 1, e = t & 1;
      int row = unit & 31, h = unit >> 5;
      const float* srow = scoF + row*129 + h*32 + e*16;
      float v[16];
      float mx = -3.4e38f;
#pragma unroll
      for (int q = 0; q < 16; ++q) { v[q] = srow[q]; mx = fmaxf(mx, v[q]); }
      mx = fmaxf(mx, __shfl_xor(mx, 1));
      float s = 0.f;
#pragma unroll
      for (int q = 0; q < 16; ++q) { v[q] = expf(v[q] - mx); s += v[q]; }
      s += __shfl_xor(s, 1);
      float inv = 1.0f / s;
      ushort_t* arow = qS + row*136 + h*32 + e*16;
#pragma unroll
      for (int q = 0; q < 16; ++q) arow[q] = f2b(v[q] * inv);
    }
    __syncthreads();
#pragma unroll
    for (int ti = 0; ti < 4; ++ti) {
      int tile = w + 4*ti;
      int h = tile >> 2, mi = (tile >> 1) & 1, ni = tile & 1;
      bf16x8 aa = *(const bf16x8*)((const char*)qS + (mi*16 + (lane & 15))*272 + h*64 + ((lane >> 4) << 4));
      bf16x8 vb = *(const bf16x8*)((const char*)vTS + (h*32 + ni*16 + (lane & 15))*80 + ((lane >> 4) << 4));
      f32x4 z = {0.f,0.f,0.f,0.f};
      f32x4 ov = MFMA(aa, vb, z);
      int col = h*32 + ni*16 + (lane & 15);
      int rb2 = mi*16 + (lane >> 4)*4;
#pragma unroll
      for (int r = 0; r < 4; ++r) {
        int row = rb2 + r;
        int ha = ((row << 8) + (col << 1)) ^ ((row & 7) << 4);
        hbS[ha >> 1] = f2b(ov[r]);
      }
    }
    __syncthreads();
    const ushort_t* Wop = wpk + 262144 + (size_t)d*16384;
#pragma unroll
    for (int tni = 0; tni < 2; ++tni) {
      int tn = 2*w + tni;
      f32x4 acc0 = {0.f,0.f,0.f,0.f}, acc1 = acc0;
#pragma unroll
      for (int tk = 0; tk < 4; ++tk) {
        bf16x8 b = *(const bf16x8*)(Wop + ((tk*8 + tn) << 9) + (lane << 3));
        int row0 = lane & 15;
        int ba0 = ((row0 << 8) + (tk << 6) + ((lane >> 4) << 4)) ^ ((row0 & 7) << 4);
        bf16x8 a0 = *(const bf16x8*)((const char*)hbS + ba0);
        acc0 = MFMA(a0, b, acc0);
        int row1 = 16 + (lane & 15);
        int ba1 = ((row1 << 8) + (tk << 6) + ((lane >> 4) << 4)) ^ ((row1 & 7) << 4);
        bf16x8 a1 = *(const bf16x8*)((const char*)hbS + ba1);
        acc1 = MFMA(a1, b, acc1);
      }
      int c = tn*16 + (lane & 15);
      int rb2 = (lane >> 4)*4;
#pragma unroll
      for (int r = 0; r < 4; ++r) {
        uF[(rb2 + r)*NC + c]      = hcurS[(rb2 + r)*NC + c]      + acc0[r];
        uF[(16 + rb2 + r)*NC + c] = hcurS[(16 + rb2 + r)*NC + c] + acc1[r];
      }
    }
    __syncthreads();
    {
      const int k = t >> 3, e = t & 7;
      float s = 0.f;
#pragma unroll
      for (int ii = 0; ii < 16; ++ii) s += uF[k*NC + e + 8*ii];
      s += __shfl_xor(s,1); s += __shfl_xor(s,2); s += __shfl_xor(s,4);
      float mu = s * (1.0f/128.0f);
      float vs = 0.f;
#pragma unroll
      for (int ii = 0; ii < 16; ++ii) { float dx = uF[k*NC + e + 8*ii] - mu; vs += dx*dx; }
      vs += __shfl_xor(vs,1); vs += __shfl_xor(vs,2); vs += __shfl_xor(vs,4);
      float rs = rsqrtf(vs*(1.0f/128.0f) + EPSF);
#pragma unroll
      for (int ii = 0; ii < 16; ++ii) {
        int o = e + 8*ii;
        float hv = (uF[k*NC + o] - mu)*rs*ln2g[d*NC + o] + ln2b[d*NC + o];
        hcurS[k*NC + o] = hv;
        int ha = ((k << 8) + (o << 1)) ^ ((k & 7) << 4);
        hbS[ha >> 1] = f2b(hv);
      }
    }
    __syncthreads();
  }
  if (t < NC) {
    float m = hcurS[t];
    for (int k = 1; k < NK; ++k) m = fmaxf(m, hcurS[k*NC + t]);
    out[(size_t)p*NC + t] = m;
  }
}

// ---------------------------------------------------------------- launcher
extern "C" void kernel_launch(void* const* d_in, const int* in_sizes, int n_in,
                              void* d_out, int out_size, void* d_ws, size_t ws_size,
                              hipStream_t stream) {
  const float* xyz    = (const float*)d_in[0];
  const float* points = (const float*)d_in[1];
  const float* w1     = (const float*)d_in[2];
  const float* g1     = (const float*)d_in[3];
  const float* b1     = (const float*)d_in[4];
  const float* w2     = (const float*)d_in[5];
  const float* g2     = (const float*)d_in[6];
  const float* b2     = (const float*)d_in[7];
  const float* w3     = (const float*)d_in[8];
  const float* g3     = (const float*)d_in[9];
  const float* b3     = (const float*)d_in[10];
  const float* wsW    = (const float*)d_in[11];
  const float* wb     = (const float*)d_in[12];
  const float* alpha  = (const float*)d_in[13];
  const float* wqkv   = (const float*)d_in[14];
  const float* wo     = (const float*)d_in[15];
  const float* ln1g   = (const float*)d_in[16];
  const float* ln1b   = (const float*)d_in[17];
  const float* ln2g   = (const float*)d_in[18];
  const float* ln2b   = (const float*)d_in[19];
  float* outp = (float*)d_out;

  float* wsf   = (float*)d_ws;
  float* gnorm = wsf;                        // 786432 f
  float* stats = wsf + 786432;               // 768 f
  float* aff   = wsf + 787200;               // 768 f
  int*   knn   = (int*)(wsf + 787968);       // 262144 i  (reused as wpk after k_layer1)
  ushort_t* wpk = (ushort_t*)(wsf + 787968); // 294912 bf16
  float* h2    = wsf + 1050112;              // 16777216 f
  float* hX    = wsf + 17827328;             // 33554432 f

  hipMemsetAsync(stats, 0, 768*sizeof(float), stream);
  k_fps<<<NB, 256, 0, stream>>>(xyz, outp);
  k_knn<<<NPTS, 64, 0, stream>>>(xyz, outp, knn, gnorm);
  k_layer1<<<NM/64, 256, 0, stream>>>(points, knn, gnorm, w1, hX, stats);
  k_pack<<<294912/256, 256, 0, stream>>>(wsW, wqkv, wo, wpk);
  k_finalize<<<1, 128, 0, stream>>>(stats, g1, b1, aff, 64);
  k_layer<64><<<NM/64, 256, 0, stream>>>(hX, aff, w2, h2, stats + 256);
  k_finalize<<<1, 128, 0, stream>>>(stats + 256, g2, b2, aff + 256, 64);
  k_layer<128><<<NM/64, 256, 0, stream>>>(h2, aff + 256, w3, hX, stats + 512);
  k_finalize<<<1, 128, 0, stream>>>(stats + 512, g3, b3, aff + 512, 128);
  k_group<<<NPTS, 256, 0, stream>>>(hX, aff + 512, gnorm, wpk, wb, alpha,
                                    ln1g, ln1b, ln2g, ln2b, outp + (size_t)NB*NS*3);
}